// Round 8
// baseline (187.495 us; speedup 1.0000x reference)
//
#include <hip/hip_runtime.h>

typedef unsigned short u16;
typedef short short8 __attribute__((ext_vector_type(8)));
typedef float f32x4 __attribute__((ext_vector_type(4)));
typedef float f32x16 __attribute__((ext_vector_type(16)));
typedef unsigned short u16x4 __attribute__((ext_vector_type(4)));
typedef unsigned int u32x4 __attribute__((ext_vector_type(4)));

#define MFMA16(a, b, c) __builtin_amdgcn_mfma_f32_16x16x32_bf16((a), (b), (c), 0, 0, 0)
#define MFMA32(a, b, c) __builtin_amdgcn_mfma_f32_32x32x16_bf16((a), (b), (c), 0, 0, 0)

#if __has_builtin(__builtin_amdgcn_exp2f)
#define EXP2F(x) __builtin_amdgcn_exp2f(x)
#else
#define EXP2F(x) exp2f(x)
#endif

__device__ __forceinline__ u16 f2bf(float f) {
    unsigned u = __builtin_bit_cast(unsigned, f);
    u += 0x7FFFu + ((u >> 16) & 1u);   // RNE
    return (u16)(u >> 16);
}

__device__ __forceinline__ void async16(void* lds, const void* g) {
    __builtin_amdgcn_global_load_lds(
        (const __attribute__((address_space(1))) void*)g,
        (__attribute__((address_space(3))) void*)lds, 16, 0, 0);
}

__device__ __forceinline__ unsigned cvtpk(float lo, float hi) {
    unsigned r;
    asm("v_cvt_pk_bf16_f32 %0, %1, %2" : "=v"(r) : "v"(lo), "v"(hi));
    return r;
}
__device__ __forceinline__ void plswap(unsigned& a, unsigned& b) {
    asm("v_permlane32_swap_b32 %0, %1" : "+v"(a), "+v"(b));
}

// pack one S^T tile (16 f32, keys crow(r,hi)) into two A-fragments (ksl=0,1)
__device__ __forceinline__ void packP(const f32x16& s, short8& f0, short8& f1) {
    u32x4 u0, u1;
    {
        unsigned a = cvtpk(s[0], s[1]), b = cvtpk(s[4], s[5]);
        plswap(a, b);
        unsigned c = cvtpk(s[2], s[3]), d = cvtpk(s[6], s[7]);
        plswap(c, d);
        u0[0] = a; u0[1] = c; u0[2] = b; u0[3] = d;
    }
    {
        unsigned a = cvtpk(s[8], s[9]), b = cvtpk(s[12], s[13]);
        plswap(a, b);
        unsigned c = cvtpk(s[10], s[11]), d = cvtpk(s[14], s[15]);
        plswap(c, d);
        u1[0] = a; u1[1] = c; u1[2] = b; u1[3] = d;
    }
    f0 = __builtin_bit_cast(short8, u0);
    f1 = __builtin_bit_cast(short8, u1);
}

// ---------------- fused cast fp32 -> bf16 for x | w_qkv (q-rows scaled) | w_out ----------
__global__ __launch_bounds__(256) void cast3(const float* __restrict__ x,
                                             const float* __restrict__ wqkv,
                                             const float* __restrict__ wout,
                                             u16* __restrict__ dst) {
    const int blk = blockIdx.x;
    const float* src;
    int idx;
    float sc = 1.0f;
    u16* out;
    if (blk < 8192) {
        src = x; out = dst; idx = (blk * 256 + threadIdx.x) * 4;
    } else if (blk < 11264) {
        src = wqkv; out = dst + (size_t)8192 * 1024;
        idx = ((blk - 8192) * 256 + threadIdx.x) * 4;
        if (idx < 1024 * 1024) sc = 0.18033688011112042f;  // 0.125 * log2(e) on q-rows
    } else {
        src = wout; out = dst + (size_t)11264 * 1024;
        idx = ((blk - 11264) * 256 + threadIdx.x) * 4;
    }
    float4 v = *(const float4*)(src + idx);
    u16x4 r;
    r[0] = f2bf(v.x * sc); r[1] = f2bf(v.y * sc);
    r[2] = f2bf(v.z * sc); r[3] = f2bf(v.w * sc);
    *(u16x4*)(out + idx) = r;
}

// ---------------- GEMM1a: Q|K projection, 256x256 tile, BK=64, 8 waves -------------------
// C[8192, 0..2047] = A * w_qk^T -> qkb (ld 2048). Grid 32x8 = 256 = EXACTLY one full
// round at 1 block/CU (perfect fill). Stage-early double buffer, T2 XOR swizzle.
__global__ __launch_bounds__(512, 2) void gemm256(const u16* __restrict__ A,
                                                  const u16* __restrict__ B,
                                                  u16* __restrict__ qk) {
    __shared__ u16 lds[2][2][16384];   // [dbuf][A=0/B=1][256 rows x 64 cols]
    const int tid = threadIdx.x;
    const int l = tid & 63;
    const int w = tid >> 6;
    const int g = l >> 4, lo = l & 15;
    const int wrow = w >> 2, wcol = w & 3;            // 2 x 4 wave grid
    const int tm = blockIdx.x & 31, tn = blockIdx.x >> 5;   // 256 = 32 x 8, tm fast
    const int rowBase = tm << 8, colBase = tn << 8;

    const int srow = tid >> 3;                                        // 0..63
    const int scol = (((tid * 16) ^ (((tid >> 3) & 7) << 4)) & 127) >> 1;  // pre-swizzled col
    const u16* pa = A + (size_t)(rowBase + srow) * 1024 + scol;
    const u16* pb = B + (size_t)(colBase + srow) * 1024 + scol;
    const int ldsOff = tid * 16;

    int abase[2], bbase[2];
#pragma unroll
    for (int k = 0; k < 2; ++k) {
        abase[k] = (((wrow * 128 + lo) * 128 + k * 64 + g * 16) ^ ((lo & 7) << 4));
        bbase[k] = (((wcol * 64 + lo) * 128 + k * 64 + g * 16) ^ ((lo & 7) << 4));
    }

    f32x4 acc[8][4] = {};

#define STAGE256(buf, kt)                                                                   \
    {                                                                                       \
        const u16* sa = pa + (kt) * 64;                                                     \
        const u16* sb = pb + (kt) * 64;                                                     \
        _Pragma("unroll")                                                                   \
        for (int i = 0; i < 4; ++i) {                                                       \
            async16((char*)lds[buf][0] + ldsOff + i * 8192, sa + (size_t)i * 64 * 1024);    \
            async16((char*)lds[buf][1] + ldsOff + i * 8192, sb + (size_t)i * 64 * 1024);    \
        }                                                                                   \
    }

    STAGE256(0, 0);
    __syncthreads();

    for (int kt = 0; kt < 16; ++kt) {
        const int cur = kt & 1;
        if (kt < 15) STAGE256(cur ^ 1, kt + 1);        // issue BEFORE compute (T14/T3)
        const char* la = (const char*)lds[cur][0];
        const char* lb = (const char*)lds[cur][1];

        short8 bf[4][2], af[4][2];
#pragma unroll
        for (int n = 0; n < 4; ++n)
#pragma unroll
            for (int k = 0; k < 2; ++k)
                bf[n][k] = *(const short8*)(lb + bbase[k] + n * 2048);
#pragma unroll
        for (int m = 0; m < 4; ++m)
#pragma unroll
            for (int k = 0; k < 2; ++k)
                af[m][k] = *(const short8*)(la + abase[k] + m * 2048);
        __builtin_amdgcn_s_setprio(1);
#pragma unroll
        for (int m = 0; m < 4; ++m)
#pragma unroll
            for (int n = 0; n < 4; ++n) {
                acc[m][n] = MFMA16(af[m][0], bf[n][0], acc[m][n]);
                acc[m][n] = MFMA16(af[m][1], bf[n][1], acc[m][n]);
            }
        __builtin_amdgcn_s_setprio(0);
#pragma unroll
        for (int m = 0; m < 4; ++m)
#pragma unroll
            for (int k = 0; k < 2; ++k)
                af[m][k] = *(const short8*)(la + abase[k] + (m + 4) * 2048);
        __builtin_amdgcn_s_setprio(1);
#pragma unroll
        for (int m = 0; m < 4; ++m)
#pragma unroll
            for (int n = 0; n < 4; ++n) {
                acc[m + 4][n] = MFMA16(af[m][0], bf[n][0], acc[m + 4][n]);
                acc[m + 4][n] = MFMA16(af[m][1], bf[n][1], acc[m + 4][n]);
            }
        __builtin_amdgcn_s_setprio(0);
        __syncthreads();   // drains this iter's stage (issued one full compute ago)
    }
#undef STAGE256

    // ---- epilogue: Q|K -> qkb (ld 2048) ----
#pragma unroll
    for (int n = 0; n < 4; ++n) {
        const int c = colBase + wcol * 64 + n * 16 + lo;
#pragma unroll
        for (int m = 0; m < 8; ++m) {
            const int r0 = rowBase + wrow * 128 + m * 16 + g * 4;
#pragma unroll
            for (int i = 0; i < 4; ++i)
                qk[(size_t)(r0 + i) * 2048 + c] = f2bf(acc[m][n][i]);
        }
    }
}

// ---------------- GEMM1b: V projection, 128x128 m97 structure, transposed epilogue -------
// C[8192, c=0..1023] = A * w_v^T -> vtg [bh*64+d][2048]. Grid 64x8 = 512 = exactly
// 2 rounds at 2 blocks/CU.
__global__ __launch_bounds__(256, 2) void gemmV(const u16* __restrict__ A,
                                                const u16* __restrict__ Bv,
                                                u16* __restrict__ vt) {
    __shared__ u16 As[128 * 32];
    __shared__ u16 Bs[128 * 32];
    const int tid = threadIdx.x;
    const int w = tid >> 6, l = tid & 63;
    const int g = l >> 4, lo = l & 15;
    const int tm = blockIdx.x & 63, tn = blockIdx.x >> 6;   // 512 = 64 x 8, tm fast
    const int rowBase = tm << 7, colBase = tn << 7;
    const int wrow = w >> 1, wcol = w & 1;

    f32x4 acc[4][4] = {};

    const int srow = l >> 2;
    const int scol = (l & 3) * 8;
    for (int kt = 0; kt < 32; ++kt) {
        const int kbase = kt * 32 + scol;
#pragma unroll
        for (int it = 0; it < 2; ++it) {
            const int seg = it * 4 + w;
            const int r = seg * 16 + srow;
            async16(&As[seg * 512], &A[(size_t)(rowBase + r) * 1024 + kbase]);
            async16(&Bs[seg * 512], &Bv[(size_t)(colBase + r) * 1024 + kbase]);
        }
        __syncthreads();
        short8 af[4], bf[4];
#pragma unroll
        for (int mi = 0; mi < 4; ++mi)
            af[mi] = *(const short8*)&As[(wrow * 64 + mi * 16 + lo) * 32 + g * 8];
#pragma unroll
        for (int ni = 0; ni < 4; ++ni)
            bf[ni] = *(const short8*)&Bs[(wcol * 64 + ni * 16 + lo) * 32 + g * 8];
#pragma unroll
        for (int mi = 0; mi < 4; ++mi)
#pragma unroll
            for (int ni = 0; ni < 4; ++ni)
                acc[mi][ni] = MFMA16(af[mi], bf[ni], acc[mi][ni]);
        __syncthreads();
    }

    // transposed epilogue -> vtg [(b*16+h)*64+d][2048]
    const int b = rowBase >> 11;
#pragma unroll
    for (int ni = 0; ni < 4; ++ni) {
        const int c = colBase + wcol * 64 + ni * 16 + lo;   // 0..1023
        const int hh = c >> 6, d = c & 63;
        u16* vrow = vt + ((size_t)((b * 16 + hh) * 64 + d)) * 2048;
#pragma unroll
        for (int mi = 0; mi < 4; ++mi) {
            const int r0 = rowBase + wrow * 64 + mi * 16 + g * 4;
            u16x4 pk;
#pragma unroll
            for (int i = 0; i < 4; ++i) pk[i] = f2bf(acc[mi][ni][i]);
            *(u16x4*)(vrow + (r0 & 2047)) = pk;
        }
    }
}

// ---------------- GEMM2: C = A[M,K] * B[N,K]^T  (m97 structure, fp32+bias epilogue) ------
__global__ __launch_bounds__(256, 2) void gemm_bt(const u16* __restrict__ A,
                                                  const u16* __restrict__ B,
                                                  float* __restrict__ Cf,
                                                  const float* __restrict__ bias,
                                                  int M, int N, int K) {
    __shared__ u16 As[128 * 32];
    __shared__ u16 Bs[128 * 32];
    const int tid = threadIdx.x;
    const int w = tid >> 6, l = tid & 63;
    const int g = l >> 4, lo = l & 15;
    const int mtiles = M >> 7;
    const int tm = blockIdx.x % mtiles, tn = blockIdx.x / mtiles;
    const int rowBase = tm << 7, colBase = tn << 7;
    const int wrow = w >> 1, wcol = w & 1;

    f32x4 acc[4][4] = {};

    const int srow = l >> 2;
    const int scol = (l & 3) * 8;
    const int nk = K >> 5;
    for (int kt = 0; kt < nk; ++kt) {
        const int kbase = kt * 32 + scol;
#pragma unroll
        for (int it = 0; it < 2; ++it) {
            const int seg = it * 4 + w;
            const int r = seg * 16 + srow;
            async16(&As[seg * 512], &A[(size_t)(rowBase + r) * K + kbase]);
            async16(&Bs[seg * 512], &B[(size_t)(colBase + r) * K + kbase]);
        }
        __syncthreads();
        short8 af[4], bf[4];
#pragma unroll
        for (int mi = 0; mi < 4; ++mi)
            af[mi] = *(const short8*)&As[(wrow * 64 + mi * 16 + lo) * 32 + g * 8];
#pragma unroll
        for (int ni = 0; ni < 4; ++ni)
            bf[ni] = *(const short8*)&Bs[(wcol * 64 + ni * 16 + lo) * 32 + g * 8];
#pragma unroll
        for (int mi = 0; mi < 4; ++mi)
#pragma unroll
            for (int ni = 0; ni < 4; ++ni)
                acc[mi][ni] = MFMA16(af[mi], bf[ni], acc[mi][ni]);
        __syncthreads();
    }

#pragma unroll
    for (int ni = 0; ni < 4; ++ni) {
        const int c = colBase + wcol * 64 + ni * 16 + lo;
        const float bv = bias[c];
#pragma unroll
        for (int mi = 0; mi < 4; ++mi) {
            const int r0 = rowBase + wrow * 64 + mi * 16 + g * 4;
#pragma unroll
            for (int i = 0; i < 4; ++i)
                Cf[(size_t)(r0 + i) * N + c] = acc[mi][ni][i] + bv;
        }
    }
}

// ---------------- flash attention (round-4 verified structure, verbatim) -----------------
__global__ __launch_bounds__(256, 4) void attn_fwd(const u16* __restrict__ qkb,
                                                   const u16* __restrict__ vtg,
                                                   u16* __restrict__ outb) {
    __shared__ u16 Ks[2][64 * 64];
    __shared__ u16 Vs[2][64 * 64];
    const int tid = threadIdx.x;
    const int w = tid >> 6, l = tid & 63;
    const int hi = l >> 5, lq = l & 31;

    const int lin = (blockIdx.x & 7) * 128 + (blockIdx.x >> 3);  // bijective XCD chunking
    const int bh = lin >> 4, qt = lin & 15;
    const int b = bh >> 4, h = bh & 15;
    const size_t rowQ = (size_t)b * 2048 + qt * 128 + w * 32;

    short8 qf[4];
#pragma unroll
    for (int ks = 0; ks < 4; ++ks)
        qf[ks] = *(const short8*)(qkb + (rowQ + lq) * 2048 + h * 64 + ks * 16 + hi * 8);

    int koff[4];
#pragma unroll
    for (int ks = 0; ks < 4; ++ks)
        koff[ks] = (lq * 128 + ks * 32 + hi * 16) ^ ((lq & 7) << 4);

    const int L0 = tid * 16, L1 = tid * 16 + 4096;
    const int kr0 = L0 >> 7, kc0 = ((L0 ^ ((kr0 & 7) << 4)) & 127) >> 1;
    const int kr1 = L1 >> 7, kc1 = ((L1 ^ ((kr1 & 7) << 4)) & 127) >> 1;
    const u16* ks0 = qkb + (size_t)(b * 2048 + kr0) * 2048 + 1024 + h * 64 + kc0;
    const u16* ks1 = qkb + (size_t)(b * 2048 + kr1) * 2048 + 1024 + h * 64 + kc1;
    const u16* vs0 = vtg + ((size_t)bh * 64 + kr0) * 2048 + kc0;
    const u16* vs1 = vtg + ((size_t)bh * 64 + kr1) * 2048 + kc1;
    const size_t KADV = (size_t)64 * 2048;

    f32x16 O0, O1, Ol;
#pragma unroll
    for (int i = 0; i < 16; ++i) { O0[i] = 0.f; O1[i] = 0.f; Ol[i] = 0.f; }
    const f32x16 Z = {};
    const short8 onesv = {16256, 16256, 16256, 16256, 16256, 16256, 16256, 16256};

    async16((char*)Ks[0] + L0, ks0); async16((char*)Ks[0] + L1, ks1);
    async16((char*)Vs[0] + L0, vs0); async16((char*)Vs[0] + L1, vs1);
    ks0 += KADV; ks1 += KADV; vs0 += 64; vs1 += 64;

    int cur = 0;
    for (int kt = 0; kt < 32; ++kt) {
        __syncthreads();
        if (kt < 31) {
            const int nx = cur ^ 1;
            async16((char*)Ks[nx] + L0, ks0); async16((char*)Ks[nx] + L1, ks1);
            async16((char*)Vs[nx] + L0, vs0); async16((char*)Vs[nx] + L1, vs1);
            ks0 += KADV; ks1 += KADV; vs0 += 64; vs1 += 64;
        }
        const char* kb = (const char*)Ks[cur];
        const char* vb = (const char*)Vs[cur];

#pragma unroll
        for (int t = 0; t < 2; ++t) {
            const int tb = t * 4096;
            __builtin_amdgcn_s_setprio(1);
            f32x16 s = MFMA32(*(const short8*)(kb + koff[0] + tb), qf[0], Z);
            s = MFMA32(*(const short8*)(kb + koff[1] + tb), qf[1], s);
            s = MFMA32(*(const short8*)(kb + koff[2] + tb), qf[2], s);
            s = MFMA32(*(const short8*)(kb + koff[3] + tb), qf[3], s);
            __builtin_amdgcn_s_setprio(0);

#pragma unroll
            for (int i = 0; i < 16; ++i) s[i] = EXP2F(s[i]);

            short8 p0, p1;
            packP(s, p0, p1);

            __builtin_amdgcn_s_setprio(1);
            Ol = MFMA32(p0, onesv, Ol);
            Ol = MFMA32(p1, onesv, Ol);
            O0 = MFMA32(p0, *(const short8*)(vb + koff[t * 2]), O0);
            O1 = MFMA32(p0, *(const short8*)(vb + koff[t * 2] + 4096), O1);
            O0 = MFMA32(p1, *(const short8*)(vb + koff[t * 2 + 1]), O0);
            O1 = MFMA32(p1, *(const short8*)(vb + koff[t * 2 + 1] + 4096), O1);
            __builtin_amdgcn_s_setprio(0);
        }
        cur ^= 1;
    }

#pragma unroll
    for (int r = 0; r < 16; ++r) {
        const int qrow = (r & 3) + 8 * (r >> 2) + 4 * hi;
        const float linv = 1.0f / Ol[r];
        u16* op = outb + (rowQ + qrow) * 1024 + h * 64 + lq;
        op[0] = f2bf(O0[r] * linv);
        op[32] = f2bf(O1[r] * linv);
    }
}

// ---------------- launch ----------------------------------------------------------------
extern "C" void kernel_launch(void* const* d_in, const int* in_sizes, int n_in,
                              void* d_out, int out_size, void* d_ws, size_t ws_size,
                              hipStream_t stream) {
    const float* x     = (const float*)d_in[0];   // [4,2048,1024]
    const float* w_qkv = (const float*)d_in[1];   // [3072,1024]
    const float* w_out = (const float*)d_in[2];   // [1024,1024]
    const float* b_out = (const float*)d_in[3];   // [1024]
    float* out = (float*)d_out;                   // [4,2048,1024] fp32

    u16* xb    = (u16*)d_ws;                              // 8192*1024
    u16* wqkvb = xb    + (size_t)8192 * 1024;             // 3072*1024
    u16* woutb = wqkvb + (size_t)3072 * 1024;             // 1024*1024
    u16* qkb   = woutb + (size_t)1024 * 1024;             // 8192*2048 (Q|K)
    u16* vtg   = qkb   + (size_t)8192 * 2048;             // 64*64*2048 (V^T per bh)
    u16* attb  = vtg   + (size_t)64 * 64 * 2048;          // 8192*1024
    // total ws use: 92,274,688 bytes

    cast3<<<12288, 256, 0, stream>>>(x, w_qkv, w_out, xb);

    gemm256<<<256, 512, 0, stream>>>(xb, wqkvb, qkb);                 // Q|K: 1 perfect round
    gemmV<<<512, 256, 0, stream>>>(xb, wqkvb + (size_t)2048 * 1024, vtg);  // V: 2 perfect rounds

    attn_fwd<<<1024, 256, 0, stream>>>(qkb, vtg, attb);

    gemm_bt<<<dim3((8192 / 128) * (1024 / 128)), 256, 0, stream>>>(
        attb, woutb, out, b_out, 8192, 1024, 1024);
}

// Round 9
// 186.308 us; speedup vs baseline: 1.0064x; 1.0064x over previous
//
#include <hip/hip_runtime.h>

typedef unsigned short u16;
typedef short short8 __attribute__((ext_vector_type(8)));
typedef float f32x4 __attribute__((ext_vector_type(4)));
typedef float f32x16 __attribute__((ext_vector_type(16)));
typedef unsigned short u16x4 __attribute__((ext_vector_type(4)));
typedef unsigned int u32x4 __attribute__((ext_vector_type(4)));

#define MFMA16(a, b, c) __builtin_amdgcn_mfma_f32_16x16x32_bf16((a), (b), (c), 0, 0, 0)
#define MFMA32(a, b, c) __builtin_amdgcn_mfma_f32_32x32x16_bf16((a), (b), (c), 0, 0, 0)

#if __has_builtin(__builtin_amdgcn_exp2f)
#define EXP2F(x) __builtin_amdgcn_exp2f(x)
#else
#define EXP2F(x) exp2f(x)
#endif

__device__ __forceinline__ u16 f2bf(float f) {
    unsigned u = __builtin_bit_cast(unsigned, f);
    u += 0x7FFFu + ((u >> 16) & 1u);   // RNE
    return (u16)(u >> 16);
}

__device__ __forceinline__ void async16(void* lds, const void* g) {
    __builtin_amdgcn_global_load_lds(
        (const __attribute__((address_space(1))) void*)g,
        (__attribute__((address_space(3))) void*)lds, 16, 0, 0);
}

__device__ __forceinline__ unsigned cvtpk(float lo, float hi) {
    unsigned r;
    asm("v_cvt_pk_bf16_f32 %0, %1, %2" : "=v"(r) : "v"(lo), "v"(hi));
    return r;
}
__device__ __forceinline__ void plswap(unsigned& a, unsigned& b) {
    asm("v_permlane32_swap_b32 %0, %1" : "+v"(a), "+v"(b));
}

// pack one S^T tile (16 f32, keys crow(r,hi)) into two A-fragments (ksl=0,1)
__device__ __forceinline__ void packP(const f32x16& s, short8& f0, short8& f1) {
    u32x4 u0, u1;
    {
        unsigned a = cvtpk(s[0], s[1]), b = cvtpk(s[4], s[5]);
        plswap(a, b);
        unsigned c = cvtpk(s[2], s[3]), d = cvtpk(s[6], s[7]);
        plswap(c, d);
        u0[0] = a; u0[1] = c; u0[2] = b; u0[3] = d;
    }
    {
        unsigned a = cvtpk(s[8], s[9]), b = cvtpk(s[12], s[13]);
        plswap(a, b);
        unsigned c = cvtpk(s[10], s[11]), d = cvtpk(s[14], s[15]);
        plswap(c, d);
        u1[0] = a; u1[1] = c; u1[2] = b; u1[3] = d;
    }
    f0 = __builtin_bit_cast(short8, u0);
    f1 = __builtin_bit_cast(short8, u1);
}

// ---------------- fused cast fp32 -> bf16 for x | w_qkv (q-rows scaled) | w_out ----------
__global__ __launch_bounds__(256) void cast3(const float* __restrict__ x,
                                             const float* __restrict__ wqkv,
                                             const float* __restrict__ wout,
                                             u16* __restrict__ dst) {
    const int blk = blockIdx.x;
    const float* src;
    int idx;
    float sc = 1.0f;
    u16* out;
    if (blk < 8192) {
        src = x; out = dst; idx = (blk * 256 + threadIdx.x) * 4;
    } else if (blk < 11264) {
        src = wqkv; out = dst + (size_t)8192 * 1024;
        idx = ((blk - 8192) * 256 + threadIdx.x) * 4;
        if (idx < 1024 * 1024) sc = 0.18033688011112042f;  // 0.125 * log2(e) on q-rows
    } else {
        src = wout; out = dst + (size_t)11264 * 1024;
        idx = ((blk - 11264) * 256 + threadIdx.x) * 4;
    }
    float4 v = *(const float4*)(src + idx);
    u16x4 r;
    r[0] = f2bf(v.x * sc); r[1] = f2bf(v.y * sc);
    r[2] = f2bf(v.z * sc); r[3] = f2bf(v.w * sc);
    *(u16x4*)(out + idx) = r;
}

// ---------------- GEMM1a: Q|K projection, 256x256 tile, BK=64, 8 waves -------------------
// XCD-stripe affinity: xcd = bid&7 owns A-stripes tm in [xcd*4, xcd*4+4) (2 MB, L2-fits).
// The 8 blocks sharing an A-stripe are co-resident on ONE XCD -> A fetched once per chip.
__global__ __launch_bounds__(512, 2) void gemm256(const u16* __restrict__ A,
                                                  const u16* __restrict__ B,
                                                  u16* __restrict__ qk) {
    __shared__ u16 lds[2][2][16384];   // [dbuf][A=0/B=1][256 rows x 64 cols]
    const int tid = threadIdx.x;
    const int l = tid & 63;
    const int w = tid >> 6;
    const int g = l >> 4, lo = l & 15;
    const int wrow = w >> 2, wcol = w & 3;            // 2 x 4 wave grid
    const int xcd = blockIdx.x & 7, j = blockIdx.x >> 3;   // 256 blocks = 8 XCD x 32
    const int tm = xcd * 4 + (j & 3), tn = j >> 2;         // 4 stripes per XCD, tn 0..7
    const int rowBase = tm << 8, colBase = tn << 8;

    const int srow = tid >> 3;                                        // 0..63
    const int scol = (((tid * 16) ^ (((tid >> 3) & 7) << 4)) & 127) >> 1;  // pre-swizzled col
    const u16* pa = A + (size_t)(rowBase + srow) * 1024 + scol;
    const u16* pb = B + (size_t)(colBase + srow) * 1024 + scol;
    const int ldsOff = tid * 16;

    int abase[2], bbase[2];
#pragma unroll
    for (int k = 0; k < 2; ++k) {
        abase[k] = (((wrow * 128 + lo) * 128 + k * 64 + g * 16) ^ ((lo & 7) << 4));
        bbase[k] = (((wcol * 64 + lo) * 128 + k * 64 + g * 16) ^ ((lo & 7) << 4));
    }

    f32x4 acc[8][4] = {};

#define STAGE256(buf, kt)                                                                   \
    {                                                                                       \
        const u16* sa = pa + (kt) * 64;                                                     \
        const u16* sb = pb + (kt) * 64;                                                     \
        _Pragma("unroll")                                                                   \
        for (int i = 0; i < 4; ++i) {                                                       \
            async16((char*)lds[buf][0] + ldsOff + i * 8192, sa + (size_t)i * 64 * 1024);    \
            async16((char*)lds[buf][1] + ldsOff + i * 8192, sb + (size_t)i * 64 * 1024);    \
        }                                                                                   \
    }

    STAGE256(0, 0);
    __syncthreads();

    for (int kt = 0; kt < 16; ++kt) {
        const int cur = kt & 1;
        if (kt < 15) STAGE256(cur ^ 1, kt + 1);        // issue BEFORE compute (T14/T3)
        const char* la = (const char*)lds[cur][0];
        const char* lb = (const char*)lds[cur][1];

        short8 bf[4][2], af[4][2];
#pragma unroll
        for (int n = 0; n < 4; ++n)
#pragma unroll
            for (int k = 0; k < 2; ++k)
                bf[n][k] = *(const short8*)(lb + bbase[k] + n * 2048);
#pragma unroll
        for (int m = 0; m < 4; ++m)
#pragma unroll
            for (int k = 0; k < 2; ++k)
                af[m][k] = *(const short8*)(la + abase[k] + m * 2048);
        __builtin_amdgcn_s_setprio(1);
#pragma unroll
        for (int m = 0; m < 4; ++m)
#pragma unroll
            for (int n = 0; n < 4; ++n) {
                acc[m][n] = MFMA16(af[m][0], bf[n][0], acc[m][n]);
                acc[m][n] = MFMA16(af[m][1], bf[n][1], acc[m][n]);
            }
        __builtin_amdgcn_s_setprio(0);
#pragma unroll
        for (int m = 0; m < 4; ++m)
#pragma unroll
            for (int k = 0; k < 2; ++k)
                af[m][k] = *(const short8*)(la + abase[k] + (m + 4) * 2048);
        __builtin_amdgcn_s_setprio(1);
#pragma unroll
        for (int m = 0; m < 4; ++m)
#pragma unroll
            for (int n = 0; n < 4; ++n) {
                acc[m + 4][n] = MFMA16(af[m][0], bf[n][0], acc[m + 4][n]);
                acc[m + 4][n] = MFMA16(af[m][1], bf[n][1], acc[m + 4][n]);
            }
        __builtin_amdgcn_s_setprio(0);
        __syncthreads();   // drains this iter's stage (issued one full compute ago)
    }
#undef STAGE256

    // ---- epilogue: Q|K -> qkb (ld 2048) ----
#pragma unroll
    for (int n = 0; n < 4; ++n) {
        const int c = colBase + wcol * 64 + n * 16 + lo;
#pragma unroll
        for (int m = 0; m < 8; ++m) {
            const int r0 = rowBase + wrow * 128 + m * 16 + g * 4;
#pragma unroll
            for (int i = 0; i < 4; ++i)
                qk[(size_t)(r0 + i) * 2048 + c] = f2bf(acc[m][n][i]);
        }
    }
}

// ---------------- GEMM1b: V projection, 128x128 m97 structure, transposed epilogue -------
// 512 blocks = 8 XCD x 64: each XCD owns 8 A-stripes (2 MB, L2-fits).
__global__ __launch_bounds__(256, 2) void gemmV(const u16* __restrict__ A,
                                                const u16* __restrict__ Bv,
                                                u16* __restrict__ vt) {
    __shared__ u16 As[128 * 32];
    __shared__ u16 Bs[128 * 32];
    const int tid = threadIdx.x;
    const int w = tid >> 6, l = tid & 63;
    const int g = l >> 4, lo = l & 15;
    const int xcd = blockIdx.x & 7, j = blockIdx.x >> 3;   // 8 XCD x 64
    const int tm = xcd * 8 + (j & 7), tn = j >> 3;         // 8 stripes per XCD, tn 0..7
    const int rowBase = tm << 7, colBase = tn << 7;
    const int wrow = w >> 1, wcol = w & 1;

    f32x4 acc[4][4] = {};

    const int srow = l >> 2;
    const int scol = (l & 3) * 8;
    for (int kt = 0; kt < 32; ++kt) {
        const int kbase = kt * 32 + scol;
#pragma unroll
        for (int it = 0; it < 2; ++it) {
            const int seg = it * 4 + w;
            const int r = seg * 16 + srow;
            async16(&As[seg * 512], &A[(size_t)(rowBase + r) * 1024 + kbase]);
            async16(&Bs[seg * 512], &Bv[(size_t)(colBase + r) * 1024 + kbase]);
        }
        __syncthreads();
        short8 af[4], bf[4];
#pragma unroll
        for (int mi = 0; mi < 4; ++mi)
            af[mi] = *(const short8*)&As[(wrow * 64 + mi * 16 + lo) * 32 + g * 8];
#pragma unroll
        for (int ni = 0; ni < 4; ++ni)
            bf[ni] = *(const short8*)&Bs[(wcol * 64 + ni * 16 + lo) * 32 + g * 8];
#pragma unroll
        for (int mi = 0; mi < 4; ++mi)
#pragma unroll
            for (int ni = 0; ni < 4; ++ni)
                acc[mi][ni] = MFMA16(af[mi], bf[ni], acc[mi][ni]);
        __syncthreads();
    }

    // transposed epilogue -> vtg [(b*16+h)*64+d][2048]
    const int b = rowBase >> 11;
#pragma unroll
    for (int ni = 0; ni < 4; ++ni) {
        const int c = colBase + wcol * 64 + ni * 16 + lo;   // 0..1023
        const int hh = c >> 6, d = c & 63;
        u16* vrow = vt + ((size_t)((b * 16 + hh) * 64 + d)) * 2048;
#pragma unroll
        for (int mi = 0; mi < 4; ++mi) {
            const int r0 = rowBase + wrow * 64 + mi * 16 + g * 4;
            u16x4 pk;
#pragma unroll
            for (int i = 0; i < 4; ++i) pk[i] = f2bf(acc[mi][ni][i]);
            *(u16x4*)(vrow + (r0 & 2047)) = pk;
        }
    }
}

// ---------------- GEMM2: C = A[M,K] * B[N,K]^T  (m97 structure, fp32+bias epilogue) ------
// XCD-stripe affinity: S = mtiles/8 stripes per XCD.
__global__ __launch_bounds__(256, 2) void gemm_bt(const u16* __restrict__ A,
                                                  const u16* __restrict__ B,
                                                  float* __restrict__ Cf,
                                                  const float* __restrict__ bias,
                                                  int M, int N, int K) {
    __shared__ u16 As[128 * 32];
    __shared__ u16 Bs[128 * 32];
    const int tid = threadIdx.x;
    const int w = tid >> 6, l = tid & 63;
    const int g = l >> 4, lo = l & 15;
    const int mtiles = M >> 7;
    const int S = mtiles >> 3;
    const int xcd = blockIdx.x & 7, j = blockIdx.x >> 3;
    const int tm = xcd * S + (j % S), tn = j / S;
    const int rowBase = tm << 7, colBase = tn << 7;
    const int wrow = w >> 1, wcol = w & 1;

    f32x4 acc[4][4] = {};

    const int srow = l >> 2;
    const int scol = (l & 3) * 8;
    const int nk = K >> 5;
    for (int kt = 0; kt < nk; ++kt) {
        const int kbase = kt * 32 + scol;
#pragma unroll
        for (int it = 0; it < 2; ++it) {
            const int seg = it * 4 + w;
            const int r = seg * 16 + srow;
            async16(&As[seg * 512], &A[(size_t)(rowBase + r) * K + kbase]);
            async16(&Bs[seg * 512], &B[(size_t)(colBase + r) * K + kbase]);
        }
        __syncthreads();
        short8 af[4], bf[4];
#pragma unroll
        for (int mi = 0; mi < 4; ++mi)
            af[mi] = *(const short8*)&As[(wrow * 64 + mi * 16 + lo) * 32 + g * 8];
#pragma unroll
        for (int ni = 0; ni < 4; ++ni)
            bf[ni] = *(const short8*)&Bs[(wcol * 64 + ni * 16 + lo) * 32 + g * 8];
#pragma unroll
        for (int mi = 0; mi < 4; ++mi)
#pragma unroll
            for (int ni = 0; ni < 4; ++ni)
                acc[mi][ni] = MFMA16(af[mi], bf[ni], acc[mi][ni]);
        __syncthreads();
    }

#pragma unroll
    for (int ni = 0; ni < 4; ++ni) {
        const int c = colBase + wcol * 64 + ni * 16 + lo;
        const float bv = bias[c];
#pragma unroll
        for (int mi = 0; mi < 4; ++mi) {
            const int r0 = rowBase + wrow * 64 + mi * 16 + g * 4;
#pragma unroll
            for (int i = 0; i < 4; ++i)
                Cf[(size_t)(r0 + i) * N + c] = acc[mi][ni][i] + bv;
        }
    }
}

// ---------------- flash attention (round-4 verified structure, verbatim) -----------------
__global__ __launch_bounds__(256, 4) void attn_fwd(const u16* __restrict__ qkb,
                                                   const u16* __restrict__ vtg,
                                                   u16* __restrict__ outb) {
    __shared__ u16 Ks[2][64 * 64];
    __shared__ u16 Vs[2][64 * 64];
    const int tid = threadIdx.x;
    const int w = tid >> 6, l = tid & 63;
    const int hi = l >> 5, lq = l & 31;

    const int lin = (blockIdx.x & 7) * 128 + (blockIdx.x >> 3);  // bijective XCD chunking
    const int bh = lin >> 4, qt = lin & 15;
    const int b = bh >> 4, h = bh & 15;
    const size_t rowQ = (size_t)b * 2048 + qt * 128 + w * 32;

    short8 qf[4];
#pragma unroll
    for (int ks = 0; ks < 4; ++ks)
        qf[ks] = *(const short8*)(qkb + (rowQ + lq) * 2048 + h * 64 + ks * 16 + hi * 8);

    int koff[4];
#pragma unroll
    for (int ks = 0; ks < 4; ++ks)
        koff[ks] = (lq * 128 + ks * 32 + hi * 16) ^ ((lq & 7) << 4);

    const int L0 = tid * 16, L1 = tid * 16 + 4096;
    const int kr0 = L0 >> 7, kc0 = ((L0 ^ ((kr0 & 7) << 4)) & 127) >> 1;
    const int kr1 = L1 >> 7, kc1 = ((L1 ^ ((kr1 & 7) << 4)) & 127) >> 1;
    const u16* ks0 = qkb + (size_t)(b * 2048 + kr0) * 2048 + 1024 + h * 64 + kc0;
    const u16* ks1 = qkb + (size_t)(b * 2048 + kr1) * 2048 + 1024 + h * 64 + kc1;
    const u16* vs0 = vtg + ((size_t)bh * 64 + kr0) * 2048 + kc0;
    const u16* vs1 = vtg + ((size_t)bh * 64 + kr1) * 2048 + kc1;
    const size_t KADV = (size_t)64 * 2048;

    f32x16 O0, O1, Ol;
#pragma unroll
    for (int i = 0; i < 16; ++i) { O0[i] = 0.f; O1[i] = 0.f; Ol[i] = 0.f; }
    const f32x16 Z = {};
    const short8 onesv = {16256, 16256, 16256, 16256, 16256, 16256, 16256, 16256};

    async16((char*)Ks[0] + L0, ks0); async16((char*)Ks[0] + L1, ks1);
    async16((char*)Vs[0] + L0, vs0); async16((char*)Vs[0] + L1, vs1);
    ks0 += KADV; ks1 += KADV; vs0 += 64; vs1 += 64;

    int cur = 0;
    for (int kt = 0; kt < 32; ++kt) {
        __syncthreads();
        if (kt < 31) {
            const int nx = cur ^ 1;
            async16((char*)Ks[nx] + L0, ks0); async16((char*)Ks[nx] + L1, ks1);
            async16((char*)Vs[nx] + L0, vs0); async16((char*)Vs[nx] + L1, vs1);
            ks0 += KADV; ks1 += KADV; vs0 += 64; vs1 += 64;
        }
        const char* kb = (const char*)Ks[cur];
        const char* vb = (const char*)Vs[cur];

#pragma unroll
        for (int t = 0; t < 2; ++t) {
            const int tb = t * 4096;
            __builtin_amdgcn_s_setprio(1);
            f32x16 s = MFMA32(*(const short8*)(kb + koff[0] + tb), qf[0], Z);
            s = MFMA32(*(const short8*)(kb + koff[1] + tb), qf[1], s);
            s = MFMA32(*(const short8*)(kb + koff[2] + tb), qf[2], s);
            s = MFMA32(*(const short8*)(kb + koff[3] + tb), qf[3], s);
            __builtin_amdgcn_s_setprio(0);

#pragma unroll
            for (int i = 0; i < 16; ++i) s[i] = EXP2F(s[i]);

            short8 p0, p1;
            packP(s, p0, p1);

            __builtin_amdgcn_s_setprio(1);
            Ol = MFMA32(p0, onesv, Ol);
            Ol = MFMA32(p1, onesv, Ol);
            O0 = MFMA32(p0, *(const short8*)(vb + koff[t * 2]), O0);
            O1 = MFMA32(p0, *(const short8*)(vb + koff[t * 2] + 4096), O1);
            O0 = MFMA32(p1, *(const short8*)(vb + koff[t * 2 + 1]), O0);
            O1 = MFMA32(p1, *(const short8*)(vb + koff[t * 2 + 1] + 4096), O1);
            __builtin_amdgcn_s_setprio(0);
        }
        cur ^= 1;
    }

#pragma unroll
    for (int r = 0; r < 16; ++r) {
        const int qrow = (r & 3) + 8 * (r >> 2) + 4 * hi;
        const float linv = 1.0f / Ol[r];
        u16* op = outb + (rowQ + qrow) * 1024 + h * 64 + lq;
        op[0] = f2bf(O0[r] * linv);
        op[32] = f2bf(O1[r] * linv);
    }
}

// ---------------- launch ----------------------------------------------------------------
extern "C" void kernel_launch(void* const* d_in, const int* in_sizes, int n_in,
                              void* d_out, int out_size, void* d_ws, size_t ws_size,
                              hipStream_t stream) {
    const float* x     = (const float*)d_in[0];   // [4,2048,1024]
    const float* w_qkv = (const float*)d_in[1];   // [3072,1024]
    const float* w_out = (const float*)d_in[2];   // [1024,1024]
    const float* b_out = (const float*)d_in[3];   // [1024]
    float* out = (float*)d_out;                   // [4,2048,1024] fp32

    u16* xb    = (u16*)d_ws;                              // 8192*1024
    u16* wqkvb = xb    + (size_t)8192 * 1024;             // 3072*1024
    u16* woutb = wqkvb + (size_t)3072 * 1024;             // 1024*1024
    u16* qkb   = woutb + (size_t)1024 * 1024;             // 8192*2048 (Q|K)
    u16* vtg   = qkb   + (size_t)8192 * 2048;             // 64*64*2048 (V^T per bh)
    u16* attb  = vtg   + (size_t)64 * 64 * 2048;          // 8192*1024
    // total ws use: 92,274,688 bytes

    cast3<<<12288, 256, 0, stream>>>(x, w_qkv, w_out, xb);

    gemm256<<<256, 512, 0, stream>>>(xb, wqkvb, qkb);                 // Q|K projection
    gemmV<<<512, 256, 0, stream>>>(xb, wqkvb + (size_t)2048 * 1024, vtg);  // V projection

    attn_fwd<<<1024, 256, 0, stream>>>(qkb, vtg, attb);

    gemm_bt<<<dim3((8192 / 128) * (1024 / 128)), 256, 0, stream>>>(
        attb, woutb, out, b_out, 8192, 1024, 1024);
}

// Round 11
// 180.788 us; speedup vs baseline: 1.0371x; 1.0305x over previous
//
#include <hip/hip_runtime.h>

typedef unsigned short u16;
typedef short short8 __attribute__((ext_vector_type(8)));
typedef float f32x4 __attribute__((ext_vector_type(4)));
typedef float f32x16 __attribute__((ext_vector_type(16)));
typedef unsigned short u16x4 __attribute__((ext_vector_type(4)));
typedef unsigned int u32x4 __attribute__((ext_vector_type(4)));

#define MFMA16(a, b, c) __builtin_amdgcn_mfma_f32_16x16x32_bf16((a), (b), (c), 0, 0, 0)
#define MFMA32(a, b, c) __builtin_amdgcn_mfma_f32_32x32x16_bf16((a), (b), (c), 0, 0, 0)

#if __has_builtin(__builtin_amdgcn_exp2f)
#define EXP2F(x) __builtin_amdgcn_exp2f(x)
#else
#define EXP2F(x) exp2f(x)
#endif

__device__ __forceinline__ u16 f2bf(float f) {
    unsigned u = __builtin_bit_cast(unsigned, f);
    u += 0x7FFFu + ((u >> 16) & 1u);   // RNE
    return (u16)(u >> 16);
}

__device__ __forceinline__ void async16(void* lds, const void* g) {
    __builtin_amdgcn_global_load_lds(
        (const __attribute__((address_space(1))) void*)g,
        (__attribute__((address_space(3))) void*)lds, 16, 0, 0);
}

__device__ __forceinline__ unsigned cvtpk(float lo, float hi) {
    unsigned r;
    asm("v_cvt_pk_bf16_f32 %0, %1, %2" : "=v"(r) : "v"(lo), "v"(hi));
    return r;
}
__device__ __forceinline__ void plswap(unsigned& a, unsigned& b) {
    asm("v_permlane32_swap_b32 %0, %1" : "+v"(a), "+v"(b));
}

// pack one S^T tile (16 f32, keys crow(r,hi)) into two A-fragments (ksl=0,1)
__device__ __forceinline__ void packP(const f32x16& s, short8& f0, short8& f1) {
    u32x4 u0, u1;
    {
        unsigned a = cvtpk(s[0], s[1]), b = cvtpk(s[4], s[5]);
        plswap(a, b);
        unsigned c = cvtpk(s[2], s[3]), d = cvtpk(s[6], s[7]);
        plswap(c, d);
        u0[0] = a; u0[1] = c; u0[2] = b; u0[3] = d;
    }
    {
        unsigned a = cvtpk(s[8], s[9]), b = cvtpk(s[12], s[13]);
        plswap(a, b);
        unsigned c = cvtpk(s[10], s[11]), d = cvtpk(s[14], s[15]);
        plswap(c, d);
        u1[0] = a; u1[1] = c; u1[2] = b; u1[3] = d;
    }
    f0 = __builtin_bit_cast(short8, u0);
    f1 = __builtin_bit_cast(short8, u1);
}

// ---------------- fused cast fp32 -> bf16 for x | w_qkv (q-rows scaled) | w_out ----------
__global__ __launch_bounds__(256) void cast3(const float* __restrict__ x,
                                             const float* __restrict__ wqkv,
                                             const float* __restrict__ wout,
                                             u16* __restrict__ dst) {
    const int blk = blockIdx.x;
    const float* src;
    int idx;
    float sc = 1.0f;
    u16* out;
    if (blk < 8192) {
        src = x; out = dst; idx = (blk * 256 + threadIdx.x) * 4;
    } else if (blk < 11264) {
        src = wqkv; out = dst + (size_t)8192 * 1024;
        idx = ((blk - 8192) * 256 + threadIdx.x) * 4;
        if (idx < 1024 * 1024) sc = 0.18033688011112042f;  // 0.125 * log2(e) on q-rows
    } else {
        src = wout; out = dst + (size_t)11264 * 1024;
        idx = ((blk - 11264) * 256 + threadIdx.x) * 4;
    }
    float4 v = *(const float4*)(src + idx);
    u16x4 r;
    r[0] = f2bf(v.x * sc); r[1] = f2bf(v.y * sc);
    r[2] = f2bf(v.z * sc); r[3] = f2bf(v.w * sc);
    *(u16x4*)(out + idx) = r;
}

// ---------------- GEMM1a: Q|K projection, 256x256 tile, BK=64, 8 waves -------------------
// XCD-stripe affinity: xcd = bid&7 owns A-stripes tm in [xcd*4, xcd*4+4) (2 MB, L2-fits).
__global__ __launch_bounds__(512, 2) void gemm256(const u16* __restrict__ A,
                                                  const u16* __restrict__ B,
                                                  u16* __restrict__ qk) {
    __shared__ u16 lds[2][2][16384];   // [dbuf][A=0/B=1][256 rows x 64 cols]
    const int tid = threadIdx.x;
    const int l = tid & 63;
    const int w = tid >> 6;
    const int g = l >> 4, lo = l & 15;
    const int wrow = w >> 2, wcol = w & 3;            // 2 x 4 wave grid
    const int xcd = blockIdx.x & 7, j = blockIdx.x >> 3;   // 256 blocks = 8 XCD x 32
    const int tm = xcd * 4 + (j & 3), tn = j >> 2;         // 4 stripes per XCD, tn 0..7
    const int rowBase = tm << 8, colBase = tn << 8;

    const int srow = tid >> 3;                                        // 0..63
    const int scol = (((tid * 16) ^ (((tid >> 3) & 7) << 4)) & 127) >> 1;  // pre-swizzled col
    const u16* pa = A + (size_t)(rowBase + srow) * 1024 + scol;
    const u16* pb = B + (size_t)(colBase + srow) * 1024 + scol;
    const int ldsOff = tid * 16;

    int abase[2], bbase[2];
#pragma unroll
    for (int k = 0; k < 2; ++k) {
        abase[k] = (((wrow * 128 + lo) * 128 + k * 64 + g * 16) ^ ((lo & 7) << 4));
        bbase[k] = (((wcol * 64 + lo) * 128 + k * 64 + g * 16) ^ ((lo & 7) << 4));
    }

    f32x4 acc[8][4] = {};

#define STAGE256(buf, kt)                                                                   \
    {                                                                                       \
        const u16* sa = pa + (kt) * 64;                                                     \
        const u16* sb = pb + (kt) * 64;                                                     \
        _Pragma("unroll")                                                                   \
        for (int i = 0; i < 4; ++i) {                                                       \
            async16((char*)lds[buf][0] + ldsOff + i * 8192, sa + (size_t)i * 64 * 1024);    \
            async16((char*)lds[buf][1] + ldsOff + i * 8192, sb + (size_t)i * 64 * 1024);    \
        }                                                                                   \
    }

    STAGE256(0, 0);
    __syncthreads();

    for (int kt = 0; kt < 16; ++kt) {
        const int cur = kt & 1;
        if (kt < 15) STAGE256(cur ^ 1, kt + 1);        // issue BEFORE compute (T14/T3)
        const char* la = (const char*)lds[cur][0];
        const char* lb = (const char*)lds[cur][1];

        short8 bf[4][2], af[4][2];
#pragma unroll
        for (int n = 0; n < 4; ++n)
#pragma unroll
            for (int k = 0; k < 2; ++k)
                bf[n][k] = *(const short8*)(lb + bbase[k] + n * 2048);
#pragma unroll
        for (int m = 0; m < 4; ++m)
#pragma unroll
            for (int k = 0; k < 2; ++k)
                af[m][k] = *(const short8*)(la + abase[k] + m * 2048);
        __builtin_amdgcn_s_setprio(1);
#pragma unroll
        for (int m = 0; m < 4; ++m)
#pragma unroll
            for (int n = 0; n < 4; ++n) {
                acc[m][n] = MFMA16(af[m][0], bf[n][0], acc[m][n]);
                acc[m][n] = MFMA16(af[m][1], bf[n][1], acc[m][n]);
            }
        __builtin_amdgcn_s_setprio(0);
#pragma unroll
        for (int m = 0; m < 4; ++m)
#pragma unroll
            for (int k = 0; k < 2; ++k)
                af[m][k] = *(const short8*)(la + abase[k] + (m + 4) * 2048);
        __builtin_amdgcn_s_setprio(1);
#pragma unroll
        for (int m = 0; m < 4; ++m)
#pragma unroll
            for (int n = 0; n < 4; ++n) {
                acc[m + 4][n] = MFMA16(af[m][0], bf[n][0], acc[m + 4][n]);
                acc[m + 4][n] = MFMA16(af[m][1], bf[n][1], acc[m + 4][n]);
            }
        __builtin_amdgcn_s_setprio(0);
        __syncthreads();   // drains this iter's stage (issued one full compute ago)
    }
#undef STAGE256

    // ---- epilogue: Q|K -> qkb (ld 2048) ----
#pragma unroll
    for (int n = 0; n < 4; ++n) {
        const int c = colBase + wcol * 64 + n * 16 + lo;
#pragma unroll
        for (int m = 0; m < 8; ++m) {
            const int r0 = rowBase + wrow * 128 + m * 16 + g * 4;
#pragma unroll
            for (int i = 0; i < 4; ++i)
                qk[(size_t)(r0 + i) * 2048 + c] = f2bf(acc[m][n][i]);
        }
    }
}

// ---------------- GEMM1b: V projection, 128x128 m97 structure, transposed epilogue -------
__global__ __launch_bounds__(256, 2) void gemmV(const u16* __restrict__ A,
                                                const u16* __restrict__ Bv,
                                                u16* __restrict__ vt) {
    __shared__ u16 As[128 * 32];
    __shared__ u16 Bs[128 * 32];
    const int tid = threadIdx.x;
    const int w = tid >> 6, l = tid & 63;
    const int g = l >> 4, lo = l & 15;
    const int xcd = blockIdx.x & 7, j = blockIdx.x >> 3;   // 8 XCD x 64
    const int tm = xcd * 8 + (j & 7), tn = j >> 3;         // 8 stripes per XCD, tn 0..7
    const int rowBase = tm << 7, colBase = tn << 7;
    const int wrow = w >> 1, wcol = w & 1;

    f32x4 acc[4][4] = {};

    const int srow = l >> 2;
    const int scol = (l & 3) * 8;
    for (int kt = 0; kt < 32; ++kt) {
        const int kbase = kt * 32 + scol;
#pragma unroll
        for (int it = 0; it < 2; ++it) {
            const int seg = it * 4 + w;
            const int r = seg * 16 + srow;
            async16(&As[seg * 512], &A[(size_t)(rowBase + r) * 1024 + kbase]);
            async16(&Bs[seg * 512], &Bv[(size_t)(colBase + r) * 1024 + kbase]);
        }
        __syncthreads();
        short8 af[4], bf[4];
#pragma unroll
        for (int mi = 0; mi < 4; ++mi)
            af[mi] = *(const short8*)&As[(wrow * 64 + mi * 16 + lo) * 32 + g * 8];
#pragma unroll
        for (int ni = 0; ni < 4; ++ni)
            bf[ni] = *(const short8*)&Bs[(wcol * 64 + ni * 16 + lo) * 32 + g * 8];
#pragma unroll
        for (int mi = 0; mi < 4; ++mi)
#pragma unroll
            for (int ni = 0; ni < 4; ++ni)
                acc[mi][ni] = MFMA16(af[mi], bf[ni], acc[mi][ni]);
        __syncthreads();
    }

    // transposed epilogue -> vtg [(b*16+h)*64+d][2048]
    const int b = rowBase >> 11;
#pragma unroll
    for (int ni = 0; ni < 4; ++ni) {
        const int c = colBase + wcol * 64 + ni * 16 + lo;   // 0..1023
        const int hh = c >> 6, d = c & 63;
        u16* vrow = vt + ((size_t)((b * 16 + hh) * 64 + d)) * 2048;
#pragma unroll
        for (int mi = 0; mi < 4; ++mi) {
            const int r0 = rowBase + wrow * 64 + mi * 16 + g * 4;
            u16x4 pk;
#pragma unroll
            for (int i = 0; i < 4; ++i) pk[i] = f2bf(acc[mi][ni][i]);
            *(u16x4*)(vrow + (r0 & 2047)) = pk;
        }
    }
}

// ---------------- GEMM2: C = A[M,K] * B[N,K]^T  (m97 structure, fp32+bias epilogue) ------
__global__ __launch_bounds__(256, 2) void gemm_bt(const u16* __restrict__ A,
                                                  const u16* __restrict__ B,
                                                  float* __restrict__ Cf,
                                                  const float* __restrict__ bias,
                                                  int M, int N, int K) {
    __shared__ u16 As[128 * 32];
    __shared__ u16 Bs[128 * 32];
    const int tid = threadIdx.x;
    const int w = tid >> 6, l = tid & 63;
    const int g = l >> 4, lo = l & 15;
    const int mtiles = M >> 7;
    const int S = mtiles >> 3;
    const int xcd = blockIdx.x & 7, j = blockIdx.x >> 3;
    const int tm = xcd * S + (j % S), tn = j / S;
    const int rowBase = tm << 7, colBase = tn << 7;
    const int wrow = w >> 1, wcol = w & 1;

    f32x4 acc[4][4] = {};

    const int srow = l >> 2;
    const int scol = (l & 3) * 8;
    const int nk = K >> 5;
    for (int kt = 0; kt < nk; ++kt) {
        const int kbase = kt * 32 + scol;
#pragma unroll
        for (int it = 0; it < 2; ++it) {
            const int seg = it * 4 + w;
            const int r = seg * 16 + srow;
            async16(&As[seg * 512], &A[(size_t)(rowBase + r) * K + kbase]);
            async16(&Bs[seg * 512], &B[(size_t)(colBase + r) * K + kbase]);
        }
        __syncthreads();
        short8 af[4], bf[4];
#pragma unroll
        for (int mi = 0; mi < 4; ++mi)
            af[mi] = *(const short8*)&As[(wrow * 64 + mi * 16 + lo) * 32 + g * 8];
#pragma unroll
        for (int ni = 0; ni < 4; ++ni)
            bf[ni] = *(const short8*)&Bs[(wcol * 64 + ni * 16 + lo) * 32 + g * 8];
#pragma unroll
        for (int mi = 0; mi < 4; ++mi)
#pragma unroll
            for (int ni = 0; ni < 4; ++ni)
                acc[mi][ni] = MFMA16(af[mi], bf[ni], acc[mi][ni]);
        __syncthreads();
    }

#pragma unroll
    for (int ni = 0; ni < 4; ++ni) {
        const int c = colBase + wcol * 64 + ni * 16 + lo;
        const float bv = bias[c];
#pragma unroll
        for (int mi = 0; mi < 4; ++mi) {
            const int r0 = rowBase + wrow * 64 + mi * 16 + g * 4;
#pragma unroll
            for (int i = 0; i < 4; ++i)
                Cf[(size_t)(r0 + i) * N + c] = acc[mi][ni][i] + bv;
        }
    }
}

// ---------------- flash attention: 256 q-rows/block (2 subtiles), round-9 chain/subtile ---
// Per t-half: K frags read ONCE into regs -> QK+softmax+PV for subtile 0 (round-9 verified
// body, single S live), then the SAME kf/vf regs feed subtile 1. LDS traffic per CU halves.
// grid 512 (XCD-bijective: 8 heads/XCD), block 256 = 4 waves, KVBLK 64, 2 blocks/CU.
__global__ __launch_bounds__(256, 2) void attn_fwd(const u16* __restrict__ qkb,
                                                   const u16* __restrict__ vtg,
                                                   u16* __restrict__ outb) {
    __shared__ u16 Ks[2][64 * 64];
    __shared__ u16 Vs[2][64 * 64];
    const int tid = threadIdx.x;
    const int w = tid >> 6, l = tid & 63;
    const int hi = l >> 5, lq = l & 31;

    const int lin = (blockIdx.x & 7) * 64 + (blockIdx.x >> 3);  // bijective XCD chunking
    const int bh = lin >> 3, qt = lin & 7;
    const int b = bh >> 4, h = bh & 15;
    const size_t rowQ0 = (size_t)b * 2048 + qt * 256 + w * 32;  // subtile 0 rows
    const size_t rowQ1 = rowQ0 + 128;                           // subtile 1 rows

    // Q fragments (B-operand) for both subtiles; 0.125*log2e folded into w_qkv q-rows
    short8 qf0[4], qf1[4];
#pragma unroll
    for (int ks = 0; ks < 4; ++ks) {
        qf0[ks] = *(const short8*)(qkb + (rowQ0 + lq) * 2048 + h * 64 + ks * 16 + hi * 8);
        qf1[ks] = *(const short8*)(qkb + (rowQ1 + lq) * 2048 + h * 64 + ks * 16 + hi * 8);
    }

    // swizzled LDS byte offsets (row lq; +4096 = +32 rows, swizzle invariant)
    int koff[4];
#pragma unroll
    for (int ks = 0; ks < 4; ++ks)
        koff[ks] = (lq * 128 + ks * 32 + hi * 16) ^ ((lq & 7) << 4);

    // staging sources (pre-swizzled so linear global_load_lds dest yields swizzled layout)
    const int L0 = tid * 16, L1 = tid * 16 + 4096;
    const int kr0 = L0 >> 7, kc0 = ((L0 ^ ((kr0 & 7) << 4)) & 127) >> 1;
    const int kr1 = L1 >> 7, kc1 = ((L1 ^ ((kr1 & 7) << 4)) & 127) >> 1;
    const u16* ks0 = qkb + (size_t)(b * 2048 + kr0) * 2048 + 1024 + h * 64 + kc0;
    const u16* ks1 = qkb + (size_t)(b * 2048 + kr1) * 2048 + 1024 + h * 64 + kc1;
    const u16* vs0 = vtg + ((size_t)bh * 64 + kr0) * 2048 + kc0;
    const u16* vs1 = vtg + ((size_t)bh * 64 + kr1) * 2048 + kc1;
    const size_t KADV = (size_t)64 * 2048;

    f32x16 O00, O01, Ol0, O10, O11, Ol1;   // per-subtile O-halves + ones-MFMA row-sums
#pragma unroll
    for (int i = 0; i < 16; ++i) {
        O00[i] = 0.f; O01[i] = 0.f; Ol0[i] = 0.f;
        O10[i] = 0.f; O11[i] = 0.f; Ol1[i] = 0.f;
    }
    const f32x16 Z = {};
    const short8 onesv = {16256, 16256, 16256, 16256, 16256, 16256, 16256, 16256}; // bf16 1.0

    async16((char*)Ks[0] + L0, ks0); async16((char*)Ks[0] + L1, ks1);
    async16((char*)Vs[0] + L0, vs0); async16((char*)Vs[0] + L1, vs1);
    ks0 += KADV; ks1 += KADV; vs0 += 64; vs1 += 64;

    int cur = 0;
    for (int kt = 0; kt < 32; ++kt) {
        __syncthreads();   // buf[cur] staged (each wave's vmcnt drained at barrier)
        if (kt < 31) {
            const int nx = cur ^ 1;
            async16((char*)Ks[nx] + L0, ks0); async16((char*)Ks[nx] + L1, ks1);
            async16((char*)Vs[nx] + L0, vs0); async16((char*)Vs[nx] + L1, vs1);
            ks0 += KADV; ks1 += KADV; vs0 += 64; vs1 += 64;
        }
        const char* kb = (const char*)Ks[cur];
        const char* vb = (const char*)Vs[cur];

#pragma unroll
        for (int t = 0; t < 2; ++t) {                 // key-halves (32 keys each)
            const int tb = t * 4096;
            // ---- K and V fragments of this half, read ONCE for both subtiles ----
            short8 kf0 = *(const short8*)(kb + koff[0] + tb);
            short8 kf1 = *(const short8*)(kb + koff[1] + tb);
            short8 kf2 = *(const short8*)(kb + koff[2] + tb);
            short8 kf3 = *(const short8*)(kb + koff[3] + tb);
            short8 vfa = *(const short8*)(vb + koff[t * 2]);
            short8 vfb = *(const short8*)(vb + koff[t * 2] + 4096);
            short8 vfc = *(const short8*)(vb + koff[t * 2 + 1]);
            short8 vfd = *(const short8*)(vb + koff[t * 2 + 1] + 4096);

            // ======== subtile 0: round-9 verified chain (single S live) ========
            {
                __builtin_amdgcn_s_setprio(1);
                f32x16 s = MFMA32(kf0, qf0[0], Z);
                s = MFMA32(kf1, qf0[1], s);
                s = MFMA32(kf2, qf0[2], s);
                s = MFMA32(kf3, qf0[3], s);
                __builtin_amdgcn_s_setprio(0);
#pragma unroll
                for (int i = 0; i < 16; ++i) s[i] = EXP2F(s[i]);
                short8 p0, p1;
                packP(s, p0, p1);
                __builtin_amdgcn_s_setprio(1);
                Ol0 = MFMA32(p0, onesv, Ol0);
                Ol0 = MFMA32(p1, onesv, Ol0);
                O00 = MFMA32(p0, vfa, O00);
                O01 = MFMA32(p0, vfb, O01);
                O00 = MFMA32(p1, vfc, O00);
                O01 = MFMA32(p1, vfd, O01);
                __builtin_amdgcn_s_setprio(0);
            }
            // ======== subtile 1: same chain, same kf/vf regs ========
            {
                __builtin_amdgcn_s_setprio(1);
                f32x16 s = MFMA32(kf0, qf1[0], Z);
                s = MFMA32(kf1, qf1[1], s);
                s = MFMA32(kf2, qf1[2], s);
                s = MFMA32(kf3, qf1[3], s);
                __builtin_amdgcn_s_setprio(0);
#pragma unroll
                for (int i = 0; i < 16; ++i) s[i] = EXP2F(s[i]);
                short8 p0, p1;
                packP(s, p0, p1);
                __builtin_amdgcn_s_setprio(1);
                Ol1 = MFMA32(p0, onesv, Ol1);
                Ol1 = MFMA32(p1, onesv, Ol1);
                O10 = MFMA32(p0, vfa, O10);
                O11 = MFMA32(p0, vfb, O11);
                O10 = MFMA32(p1, vfc, O10);
                O11 = MFMA32(p1, vfd, O11);
                __builtin_amdgcn_s_setprio(0);
            }
        }
        cur ^= 1;
    }

    // ---- epilogue: normalize by Ol, store bf16 (both subtiles) ----
#pragma unroll
    for (int r = 0; r < 16; ++r) {
        const int qrow = (r & 3) + 8 * (r >> 2) + 4 * hi;
        {
            const float linv = 1.0f / Ol0[r];
            u16* op = outb + (rowQ0 + qrow) * 1024 + h * 64 + lq;
            op[0] = f2bf(O00[r] * linv);
            op[32] = f2bf(O01[r] * linv);
        }
        {
            const float linv = 1.0f / Ol1[r];
            u16* op = outb + (rowQ1 + qrow) * 1024 + h * 64 + lq;
            op[0] = f2bf(O10[r] * linv);
            op[32] = f2bf(O11[r] * linv);
        }
    }
}

// ---------------- launch ----------------------------------------------------------------
extern "C" void kernel_launch(void* const* d_in, const int* in_sizes, int n_in,
                              void* d_out, int out_size, void* d_ws, size_t ws_size,
                              hipStream_t stream) {
    const float* x     = (const float*)d_in[0];   // [4,2048,1024]
    const float* w_qkv = (const float*)d_in[1];   // [3072,1024]
    const float* w_out = (const float*)d_in[2];   // [1024,1024]
    const float* b_out = (const float*)d_in[3];   // [1024]
    float* out = (float*)d_out;                   // [4,2048,1024] fp32

    u16* xb    = (u16*)d_ws;                              // 8192*1024
    u16* wqkvb = xb    + (size_t)8192 * 1024;             // 3072*1024
    u16* woutb = wqkvb + (size_t)3072 * 1024;             // 1024*1024
    u16* qkb   = woutb + (size_t)1024 * 1024;             // 8192*2048 (Q|K)
    u16* vtg   = qkb   + (size_t)8192 * 2048;             // 64*64*2048 (V^T per bh)
    u16* attb  = vtg   + (size_t)64 * 64 * 2048;          // 8192*1024
    // total ws use: 92,274,688 bytes

    cast3<<<12288, 256, 0, stream>>>(x, w_qkv, w_out, xb);

    gemm256<<<256, 512, 0, stream>>>(xb, wqkvb, qkb);                 // Q|K projection
    gemmV<<<512, 256, 0, stream>>>(xb, wqkvb + (size_t)2048 * 1024, vtg);  // V projection

    attn_fwd<<<512, 256, 0, stream>>>(qkb, vtg, attb);

    gemm_bt<<<dim3((8192 / 128) * (1024 / 128)), 256, 0, stream>>>(
        attb, woutb, out, b_out, 8192, 1024, 1024);
}

// Round 12
// 178.460 us; speedup vs baseline: 1.0506x; 1.0130x over previous
//
#include <hip/hip_runtime.h>

typedef unsigned short u16;
typedef short short8 __attribute__((ext_vector_type(8)));
typedef float f32x4 __attribute__((ext_vector_type(4)));
typedef float f32x16 __attribute__((ext_vector_type(16)));
typedef unsigned short u16x4 __attribute__((ext_vector_type(4)));
typedef unsigned int u32x4 __attribute__((ext_vector_type(4)));

#define MFMA16(a, b, c) __builtin_amdgcn_mfma_f32_16x16x32_bf16((a), (b), (c), 0, 0, 0)
#define MFMA32(a, b, c) __builtin_amdgcn_mfma_f32_32x32x16_bf16((a), (b), (c), 0, 0, 0)

#if __has_builtin(__builtin_amdgcn_exp2f)
#define EXP2F(x) __builtin_amdgcn_exp2f(x)
#else
#define EXP2F(x) exp2f(x)
#endif

__device__ __forceinline__ u16 f2bf(float f) {
    unsigned u = __builtin_bit_cast(unsigned, f);
    u += 0x7FFFu + ((u >> 16) & 1u);   // RNE
    return (u16)(u >> 16);
}

__device__ __forceinline__ void async16(void* lds, const void* g) {
    __builtin_amdgcn_global_load_lds(
        (const __attribute__((address_space(1))) void*)g,
        (__attribute__((address_space(3))) void*)lds, 16, 0, 0);
}

__device__ __forceinline__ unsigned cvtpk(float lo, float hi) {
    unsigned r;
    asm("v_cvt_pk_bf16_f32 %0, %1, %2" : "=v"(r) : "v"(lo), "v"(hi));
    return r;
}
__device__ __forceinline__ void plswap(unsigned& a, unsigned& b) {
    asm("v_permlane32_swap_b32 %0, %1" : "+v"(a), "+v"(b));
}

// pack one S^T tile (16 f32, keys crow(r,hi)) into two A-fragments (ksl=0,1)
__device__ __forceinline__ void packP(const f32x16& s, short8& f0, short8& f1) {
    u32x4 u0, u1;
    {
        unsigned a = cvtpk(s[0], s[1]), b = cvtpk(s[4], s[5]);
        plswap(a, b);
        unsigned c = cvtpk(s[2], s[3]), d = cvtpk(s[6], s[7]);
        plswap(c, d);
        u0[0] = a; u0[1] = c; u0[2] = b; u0[3] = d;
    }
    {
        unsigned a = cvtpk(s[8], s[9]), b = cvtpk(s[12], s[13]);
        plswap(a, b);
        unsigned c = cvtpk(s[10], s[11]), d = cvtpk(s[14], s[15]);
        plswap(c, d);
        u1[0] = a; u1[1] = c; u1[2] = b; u1[3] = d;
    }
    f0 = __builtin_bit_cast(short8, u0);
    f1 = __builtin_bit_cast(short8, u1);
}

// ---------------- fused cast fp32 -> bf16 for x | w_qkv (q-rows scaled) | w_out ----------
__global__ __launch_bounds__(256) void cast3(const float* __restrict__ x,
                                             const float* __restrict__ wqkv,
                                             const float* __restrict__ wout,
                                             u16* __restrict__ dst) {
    const int blk = blockIdx.x;
    const float* src;
    int idx;
    float sc = 1.0f;
    u16* out;
    if (blk < 8192) {
        src = x; out = dst; idx = (blk * 256 + threadIdx.x) * 4;
    } else if (blk < 11264) {
        src = wqkv; out = dst + (size_t)8192 * 1024;
        idx = ((blk - 8192) * 256 + threadIdx.x) * 4;
        if (idx < 1024 * 1024) sc = 0.18033688011112042f;  // 0.125 * log2(e) on q-rows
    } else {
        src = wout; out = dst + (size_t)11264 * 1024;
        idx = ((blk - 11264) * 256 + threadIdx.x) * 4;
    }
    float4 v = *(const float4*)(src + idx);
    u16x4 r;
    r[0] = f2bf(v.x * sc); r[1] = f2bf(v.y * sc);
    r[2] = f2bf(v.z * sc); r[3] = f2bf(v.w * sc);
    *(u16x4*)(out + idx) = r;
}

// ---------------- GEMM1a: Q|K projection, 256x256 tile, BK=64, 8 waves -------------------
// XCD-stripe affinity: xcd = bid&7 owns A-stripes tm in [xcd*4, xcd*4+4) (2 MB, L2-fits).
__global__ __launch_bounds__(512, 2) void gemm256(const u16* __restrict__ A,
                                                  const u16* __restrict__ B,
                                                  u16* __restrict__ qk) {
    __shared__ u16 lds[2][2][16384];   // [dbuf][A=0/B=1][256 rows x 64 cols]
    const int tid = threadIdx.x;
    const int l = tid & 63;
    const int w = tid >> 6;
    const int g = l >> 4, lo = l & 15;
    const int wrow = w >> 2, wcol = w & 3;            // 2 x 4 wave grid
    const int xcd = blockIdx.x & 7, j = blockIdx.x >> 3;   // 256 blocks = 8 XCD x 32
    const int tm = xcd * 4 + (j & 3), tn = j >> 2;         // 4 stripes per XCD, tn 0..7
    const int rowBase = tm << 8, colBase = tn << 8;

    const int srow = tid >> 3;                                        // 0..63
    const int scol = (((tid * 16) ^ (((tid >> 3) & 7) << 4)) & 127) >> 1;  // pre-swizzled col
    const u16* pa = A + (size_t)(rowBase + srow) * 1024 + scol;
    const u16* pb = B + (size_t)(colBase + srow) * 1024 + scol;
    const int ldsOff = tid * 16;

    int abase[2], bbase[2];
#pragma unroll
    for (int k = 0; k < 2; ++k) {
        abase[k] = (((wrow * 128 + lo) * 128 + k * 64 + g * 16) ^ ((lo & 7) << 4));
        bbase[k] = (((wcol * 64 + lo) * 128 + k * 64 + g * 16) ^ ((lo & 7) << 4));
    }

    f32x4 acc[8][4] = {};

#define STAGE256(buf, kt)                                                                   \
    {                                                                                       \
        const u16* sa = pa + (kt) * 64;                                                     \
        const u16* sb = pb + (kt) * 64;                                                     \
        _Pragma("unroll")                                                                   \
        for (int i = 0; i < 4; ++i) {                                                       \
            async16((char*)lds[buf][0] + ldsOff + i * 8192, sa + (size_t)i * 64 * 1024);    \
            async16((char*)lds[buf][1] + ldsOff + i * 8192, sb + (size_t)i * 64 * 1024);    \
        }                                                                                   \
    }

    STAGE256(0, 0);
    __syncthreads();

    for (int kt = 0; kt < 16; ++kt) {
        const int cur = kt & 1;
        if (kt < 15) STAGE256(cur ^ 1, kt + 1);        // issue BEFORE compute (T14/T3)
        const char* la = (const char*)lds[cur][0];
        const char* lb = (const char*)lds[cur][1];

        short8 bf[4][2], af[4][2];
#pragma unroll
        for (int n = 0; n < 4; ++n)
#pragma unroll
            for (int k = 0; k < 2; ++k)
                bf[n][k] = *(const short8*)(lb + bbase[k] + n * 2048);
#pragma unroll
        for (int m = 0; m < 4; ++m)
#pragma unroll
            for (int k = 0; k < 2; ++k)
                af[m][k] = *(const short8*)(la + abase[k] + m * 2048);
        __builtin_amdgcn_s_setprio(1);
#pragma unroll
        for (int m = 0; m < 4; ++m)
#pragma unroll
            for (int n = 0; n < 4; ++n) {
                acc[m][n] = MFMA16(af[m][0], bf[n][0], acc[m][n]);
                acc[m][n] = MFMA16(af[m][1], bf[n][1], acc[m][n]);
            }
        __builtin_amdgcn_s_setprio(0);
#pragma unroll
        for (int m = 0; m < 4; ++m)
#pragma unroll
            for (int k = 0; k < 2; ++k)
                af[m][k] = *(const short8*)(la + abase[k] + (m + 4) * 2048);
        __builtin_amdgcn_s_setprio(1);
#pragma unroll
        for (int m = 0; m < 4; ++m)
#pragma unroll
            for (int n = 0; n < 4; ++n) {
                acc[m + 4][n] = MFMA16(af[m][0], bf[n][0], acc[m + 4][n]);
                acc[m + 4][n] = MFMA16(af[m][1], bf[n][1], acc[m + 4][n]);
            }
        __builtin_amdgcn_s_setprio(0);
        __syncthreads();   // drains this iter's stage (issued one full compute ago)
    }
#undef STAGE256

    // ---- epilogue: Q|K -> qkb (ld 2048) ----
#pragma unroll
    for (int n = 0; n < 4; ++n) {
        const int c = colBase + wcol * 64 + n * 16 + lo;
#pragma unroll
        for (int m = 0; m < 8; ++m) {
            const int r0 = rowBase + wrow * 128 + m * 16 + g * 4;
#pragma unroll
            for (int i = 0; i < 4; ++i)
                qk[(size_t)(r0 + i) * 2048 + c] = f2bf(acc[m][n][i]);
        }
    }
}

// ---------------- GEMM1b: V projection, 128x128 m97 structure, transposed epilogue -------
__global__ __launch_bounds__(256, 2) void gemmV(const u16* __restrict__ A,
                                                const u16* __restrict__ Bv,
                                                u16* __restrict__ vt) {
    __shared__ u16 As[128 * 32];
    __shared__ u16 Bs[128 * 32];
    const int tid = threadIdx.x;
    const int w = tid >> 6, l = tid & 63;
    const int g = l >> 4, lo = l & 15;
    const int xcd = blockIdx.x & 7, j = blockIdx.x >> 3;   // 8 XCD x 64
    const int tm = xcd * 8 + (j & 7), tn = j >> 3;         // 8 stripes per XCD, tn 0..7
    const int rowBase = tm << 7, colBase = tn << 7;
    const int wrow = w >> 1, wcol = w & 1;

    f32x4 acc[4][4] = {};

    const int srow = l >> 2;
    const int scol = (l & 3) * 8;
    for (int kt = 0; kt < 32; ++kt) {
        const int kbase = kt * 32 + scol;
#pragma unroll
        for (int it = 0; it < 2; ++it) {
            const int seg = it * 4 + w;
            const int r = seg * 16 + srow;
            async16(&As[seg * 512], &A[(size_t)(rowBase + r) * 1024 + kbase]);
            async16(&Bs[seg * 512], &Bv[(size_t)(colBase + r) * 1024 + kbase]);
        }
        __syncthreads();
        short8 af[4], bf[4];
#pragma unroll
        for (int mi = 0; mi < 4; ++mi)
            af[mi] = *(const short8*)&As[(wrow * 64 + mi * 16 + lo) * 32 + g * 8];
#pragma unroll
        for (int ni = 0; ni < 4; ++ni)
            bf[ni] = *(const short8*)&Bs[(wcol * 64 + ni * 16 + lo) * 32 + g * 8];
#pragma unroll
        for (int mi = 0; mi < 4; ++mi)
#pragma unroll
            for (int ni = 0; ni < 4; ++ni)
                acc[mi][ni] = MFMA16(af[mi], bf[ni], acc[mi][ni]);
        __syncthreads();
    }

    // transposed epilogue -> vtg [(b*16+h)*64+d][2048]
    const int b = rowBase >> 11;
#pragma unroll
    for (int ni = 0; ni < 4; ++ni) {
        const int c = colBase + wcol * 64 + ni * 16 + lo;   // 0..1023
        const int hh = c >> 6, d = c & 63;
        u16* vrow = vt + ((size_t)((b * 16 + hh) * 64 + d)) * 2048;
#pragma unroll
        for (int mi = 0; mi < 4; ++mi) {
            const int r0 = rowBase + wrow * 64 + mi * 16 + g * 4;
            u16x4 pk;
#pragma unroll
            for (int i = 0; i < 4; ++i) pk[i] = f2bf(acc[mi][ni][i]);
            *(u16x4*)(vrow + (r0 & 2047)) = pk;
        }
    }
}

// ---------------- GEMM2: C = A[M,K] * B[N,K]^T  (m97 structure, fp32+bias epilogue) ------
__global__ __launch_bounds__(256, 2) void gemm_bt(const u16* __restrict__ A,
                                                  const u16* __restrict__ B,
                                                  float* __restrict__ Cf,
                                                  const float* __restrict__ bias,
                                                  int M, int N, int K) {
    __shared__ u16 As[128 * 32];
    __shared__ u16 Bs[128 * 32];
    const int tid = threadIdx.x;
    const int w = tid >> 6, l = tid & 63;
    const int g = l >> 4, lo = l & 15;
    const int mtiles = M >> 7;
    const int S = mtiles >> 3;
    const int xcd = blockIdx.x & 7, j = blockIdx.x >> 3;
    const int tm = xcd * S + (j % S), tn = j / S;
    const int rowBase = tm << 7, colBase = tn << 7;
    const int wrow = w >> 1, wcol = w & 1;

    f32x4 acc[4][4] = {};

    const int srow = l >> 2;
    const int scol = (l & 3) * 8;
    const int nk = K >> 5;
    for (int kt = 0; kt < nk; ++kt) {
        const int kbase = kt * 32 + scol;
#pragma unroll
        for (int it = 0; it < 2; ++it) {
            const int seg = it * 4 + w;
            const int r = seg * 16 + srow;
            async16(&As[seg * 512], &A[(size_t)(rowBase + r) * K + kbase]);
            async16(&Bs[seg * 512], &B[(size_t)(colBase + r) * K + kbase]);
        }
        __syncthreads();
        short8 af[4], bf[4];
#pragma unroll
        for (int mi = 0; mi < 4; ++mi)
            af[mi] = *(const short8*)&As[(wrow * 64 + mi * 16 + lo) * 32 + g * 8];
#pragma unroll
        for (int ni = 0; ni < 4; ++ni)
            bf[ni] = *(const short8*)&Bs[(wcol * 64 + ni * 16 + lo) * 32 + g * 8];
#pragma unroll
        for (int mi = 0; mi < 4; ++mi)
#pragma unroll
            for (int ni = 0; ni < 4; ++ni)
                acc[mi][ni] = MFMA16(af[mi], bf[ni], acc[mi][ni]);
        __syncthreads();
    }

#pragma unroll
    for (int ni = 0; ni < 4; ++ni) {
        const int c = colBase + wcol * 64 + ni * 16 + lo;
        const float bv = bias[c];
#pragma unroll
        for (int mi = 0; mi < 4; ++mi) {
            const int r0 = rowBase + wrow * 64 + mi * 16 + g * 4;
#pragma unroll
            for (int i = 0; i < 4; ++i)
                Cf[(size_t)(r0 + i) * N + c] = acc[mi][ni][i] + bv;
        }
    }
}

// ---------------- flash attention: 256 q-rows/block, KVBLK=128 as 2x64 chunks ------------
// Round-11 verified per-chunk body (2 subtiles, setprio-bracketed chains) verbatim;
// KV tile doubled to 128 keys staged as two independent [64][64] chunks with identical
// per-chunk layout/swizzle -> barrier count halves (16 vs 32), stage latency amortized.
// grid 512 (XCD-bijective), block 256 = 4 waves, LDS 64 KB, 2 blocks/CU.
__global__ __launch_bounds__(256, 2) void attn_fwd(const u16* __restrict__ qkb,
                                                   const u16* __restrict__ vtg,
                                                   u16* __restrict__ outb) {
    __shared__ u16 Ks[2][2][4096];   // [dbuf][chunk][64 keys x 64 d]
    __shared__ u16 Vs[2][2][4096];   // [dbuf][chunk][64 d x 64 keys]
    const int tid = threadIdx.x;
    const int w = tid >> 6, l = tid & 63;
    const int hi = l >> 5, lq = l & 31;

    const int lin = (blockIdx.x & 7) * 64 + (blockIdx.x >> 3);  // bijective XCD chunking
    const int bh = lin >> 3, qt = lin & 7;
    const int b = bh >> 4, h = bh & 15;
    const size_t rowQ0 = (size_t)b * 2048 + qt * 256 + w * 32;  // subtile 0 rows
    const size_t rowQ1 = rowQ0 + 128;                           // subtile 1 rows

    // Q fragments (B-operand) for both subtiles; 0.125*log2e folded into w_qkv q-rows
    short8 qf0[4], qf1[4];
#pragma unroll
    for (int ks = 0; ks < 4; ++ks) {
        qf0[ks] = *(const short8*)(qkb + (rowQ0 + lq) * 2048 + h * 64 + ks * 16 + hi * 8);
        qf1[ks] = *(const short8*)(qkb + (rowQ1 + lq) * 2048 + h * 64 + ks * 16 + hi * 8);
    }

    // swizzled LDS byte offsets (row lq; +4096 = +32 rows, swizzle invariant)
    int koff[4];
#pragma unroll
    for (int ks = 0; ks < 4; ++ks)
        koff[ks] = (lq * 128 + ks * 32 + hi * 16) ^ ((lq & 7) << 4);

    // staging sources (pre-swizzled so linear global_load_lds dest yields swizzled layout)
    const int L0 = tid * 16, L1 = tid * 16 + 4096;
    const int kr0 = L0 >> 7, kc0 = ((L0 ^ ((kr0 & 7) << 4)) & 127) >> 1;
    const int kr1 = L1 >> 7, kc1 = ((L1 ^ ((kr1 & 7) << 4)) & 127) >> 1;
    const u16* ks0 = qkb + (size_t)(b * 2048 + kr0) * 2048 + 1024 + h * 64 + kc0;
    const u16* ks1 = qkb + (size_t)(b * 2048 + kr1) * 2048 + 1024 + h * 64 + kc1;
    const u16* vs0 = vtg + ((size_t)bh * 64 + kr0) * 2048 + kc0;
    const u16* vs1 = vtg + ((size_t)bh * 64 + kr1) * 2048 + kc1;
    const size_t KADV = (size_t)128 * 2048;   // 128 key-rows per tile
    const size_t CADV = (size_t)64 * 2048;    // chunk-1 key-row offset

    f32x16 O00, O01, Ol0, O10, O11, Ol1;   // per-subtile O-halves + ones-MFMA row-sums
#pragma unroll
    for (int i = 0; i < 16; ++i) {
        O00[i] = 0.f; O01[i] = 0.f; Ol0[i] = 0.f;
        O10[i] = 0.f; O11[i] = 0.f; Ol1[i] = 0.f;
    }
    const f32x16 Z = {};
    const short8 onesv = {16256, 16256, 16256, 16256, 16256, 16256, 16256, 16256}; // bf16 1.0

#define STAGEKV(buf)                                                        \
    {                                                                       \
        async16((char*)Ks[buf][0] + L0, ks0);                               \
        async16((char*)Ks[buf][0] + L1, ks1);                               \
        async16((char*)Ks[buf][1] + L0, ks0 + CADV);                        \
        async16((char*)Ks[buf][1] + L1, ks1 + CADV);                        \
        async16((char*)Vs[buf][0] + L0, vs0);                               \
        async16((char*)Vs[buf][0] + L1, vs1);                               \
        async16((char*)Vs[buf][1] + L0, vs0 + 64);                          \
        async16((char*)Vs[buf][1] + L1, vs1 + 64);                          \
        ks0 += KADV; ks1 += KADV; vs0 += 128; vs1 += 128;                   \
    }

    STAGEKV(0);

    int cur = 0;
    for (int kt = 0; kt < 16; ++kt) {      // 16 tiles x 128 keys
        __syncthreads();   // buf[cur] staged (each wave's vmcnt drained at barrier)
        if (kt < 15) STAGEKV(cur ^ 1);

#pragma unroll
        for (int c = 0; c < 2; ++c) {                 // 64-key chunks
            const char* kb = (const char*)Ks[cur][c];
            const char* vb = (const char*)Vs[cur][c];

#pragma unroll
            for (int t = 0; t < 2; ++t) {             // key-halves (32 keys each)
                const int tb = t * 4096;
                // ---- K and V fragments of this half, read ONCE for both subtiles ----
                short8 kf0 = *(const short8*)(kb + koff[0] + tb);
                short8 kf1 = *(const short8*)(kb + koff[1] + tb);
                short8 kf2 = *(const short8*)(kb + koff[2] + tb);
                short8 kf3 = *(const short8*)(kb + koff[3] + tb);
                short8 vfa = *(const short8*)(vb + koff[t * 2]);
                short8 vfb = *(const short8*)(vb + koff[t * 2] + 4096);
                short8 vfc = *(const short8*)(vb + koff[t * 2 + 1]);
                short8 vfd = *(const short8*)(vb + koff[t * 2 + 1] + 4096);

                // ======== subtile 0: verified chain (single S live) ========
                {
                    __builtin_amdgcn_s_setprio(1);
                    f32x16 s = MFMA32(kf0, qf0[0], Z);
                    s = MFMA32(kf1, qf0[1], s);
                    s = MFMA32(kf2, qf0[2], s);
                    s = MFMA32(kf3, qf0[3], s);
                    __builtin_amdgcn_s_setprio(0);
#pragma unroll
                    for (int i = 0; i < 16; ++i) s[i] = EXP2F(s[i]);
                    short8 p0, p1;
                    packP(s, p0, p1);
                    __builtin_amdgcn_s_setprio(1);
                    Ol0 = MFMA32(p0, onesv, Ol0);
                    Ol0 = MFMA32(p1, onesv, Ol0);
                    O00 = MFMA32(p0, vfa, O00);
                    O01 = MFMA32(p0, vfb, O01);
                    O00 = MFMA32(p1, vfc, O00);
                    O01 = MFMA32(p1, vfd, O01);
                    __builtin_amdgcn_s_setprio(0);
                }
                // ======== subtile 1: same chain, same kf/vf regs ========
                {
                    __builtin_amdgcn_s_setprio(1);
                    f32x16 s = MFMA32(kf0, qf1[0], Z);
                    s = MFMA32(kf1, qf1[1], s);
                    s = MFMA32(kf2, qf1[2], s);
                    s = MFMA32(kf3, qf1[3], s);
                    __builtin_amdgcn_s_setprio(0);
#pragma unroll
                    for (int i = 0; i < 16; ++i) s[i] = EXP2F(s[i]);
                    short8 p0, p1;
                    packP(s, p0, p1);
                    __builtin_amdgcn_s_setprio(1);
                    Ol1 = MFMA32(p0, onesv, Ol1);
                    Ol1 = MFMA32(p1, onesv, Ol1);
                    O10 = MFMA32(p0, vfa, O10);
                    O11 = MFMA32(p0, vfb, O11);
                    O10 = MFMA32(p1, vfc, O10);
                    O11 = MFMA32(p1, vfd, O11);
                    __builtin_amdgcn_s_setprio(0);
                }
            }
        }
        cur ^= 1;
    }
#undef STAGEKV

    // ---- epilogue: normalize by Ol, store bf16 (both subtiles) ----
#pragma unroll
    for (int r = 0; r < 16; ++r) {
        const int qrow = (r & 3) + 8 * (r >> 2) + 4 * hi;
        {
            const float linv = 1.0f / Ol0[r];
            u16* op = outb + (rowQ0 + qrow) * 1024 + h * 64 + lq;
            op[0] = f2bf(O00[r] * linv);
            op[32] = f2bf(O01[r] * linv);
        }
        {
            const float linv = 1.0f / Ol1[r];
            u16* op = outb + (rowQ1 + qrow) * 1024 + h * 64 + lq;
            op[0] = f2bf(O10[r] * linv);
            op[32] = f2bf(O11[r] * linv);
        }
    }
}

// ---------------- launch ----------------------------------------------------------------
extern "C" void kernel_launch(void* const* d_in, const int* in_sizes, int n_in,
                              void* d_out, int out_size, void* d_ws, size_t ws_size,
                              hipStream_t stream) {
    const float* x     = (const float*)d_in[0];   // [4,2048,1024]
    const float* w_qkv = (const float*)d_in[1];   // [3072,1024]
    const float* w_out = (const float*)d_in[2];   // [1024,1024]
    const float* b_out = (const float*)d_in[3];   // [1024]
    float* out = (float*)d_out;                   // [4,2048,1024] fp32

    u16* xb    = (u16*)d_ws;                              // 8192*1024
    u16* wqkvb = xb    + (size_t)8192 * 1024;             // 3072*1024
    u16* woutb = wqkvb + (size_t)3072 * 1024;             // 1024*1024
    u16* qkb   = woutb + (size_t)1024 * 1024;             // 8192*2048 (Q|K)
    u16* vtg   = qkb   + (size_t)8192 * 2048;             // 64*64*2048 (V^T per bh)
    u16* attb  = vtg   + (size_t)64 * 64 * 2048;          // 8192*1024
    // total ws use: 92,274,688 bytes

    cast3<<<12288, 256, 0, stream>>>(x, w_qkv, w_out, xb);

    gemm256<<<256, 512, 0, stream>>>(xb, wqkvb, qkb);                 // Q|K projection
    gemmV<<<512, 256, 0, stream>>>(xb, wqkvb + (size_t)2048 * 1024, vtg);  // V projection

    attn_fwd<<<512, 256, 0, stream>>>(qkb, vtg, attb);

    gemm_bt<<<dim3((8192 / 128) * (1024 / 128)), 256, 0, stream>>>(
        attb, woutb, out, b_out, 8192, 1024, 1024);
}

// Round 13
// 170.783 us; speedup vs baseline: 1.0979x; 1.0449x over previous
//
#include <hip/hip_runtime.h>

typedef unsigned short u16;
typedef short short8 __attribute__((ext_vector_type(8)));
typedef float f32x4 __attribute__((ext_vector_type(4)));
typedef float f32x16 __attribute__((ext_vector_type(16)));
typedef unsigned short u16x4 __attribute__((ext_vector_type(4)));
typedef unsigned int u32x4 __attribute__((ext_vector_type(4)));

#define MFMA16(a, b, c) __builtin_amdgcn_mfma_f32_16x16x32_bf16((a), (b), (c), 0, 0, 0)
#define MFMA32(a, b, c) __builtin_amdgcn_mfma_f32_32x32x16_bf16((a), (b), (c), 0, 0, 0)

#if __has_builtin(__builtin_amdgcn_exp2f)
#define EXP2F(x) __builtin_amdgcn_exp2f(x)
#else
#define EXP2F(x) exp2f(x)
#endif

__device__ __forceinline__ u16 f2bf(float f) {
    unsigned u = __builtin_bit_cast(unsigned, f);
    u += 0x7FFFu + ((u >> 16) & 1u);   // RNE
    return (u16)(u >> 16);
}

__device__ __forceinline__ void async16(void* lds, const void* g) {
    __builtin_amdgcn_global_load_lds(
        (const __attribute__((address_space(1))) void*)g,
        (__attribute__((address_space(3))) void*)lds, 16, 0, 0);
}

__device__ __forceinline__ unsigned cvtpk(float lo, float hi) {
    unsigned r;
    asm("v_cvt_pk_bf16_f32 %0, %1, %2" : "=v"(r) : "v"(lo), "v"(hi));
    return r;
}
__device__ __forceinline__ void plswap(unsigned& a, unsigned& b) {
    asm("v_permlane32_swap_b32 %0, %1" : "+v"(a), "+v"(b));
}

// pack one S^T tile (16 f32, keys crow(r,hi)) into two A-fragments (ksl=0,1)
__device__ __forceinline__ void packP(const f32x16& s, short8& f0, short8& f1) {
    u32x4 u0, u1;
    {
        unsigned a = cvtpk(s[0], s[1]), b = cvtpk(s[4], s[5]);
        plswap(a, b);
        unsigned c = cvtpk(s[2], s[3]), d = cvtpk(s[6], s[7]);
        plswap(c, d);
        u0[0] = a; u0[1] = c; u0[2] = b; u0[3] = d;
    }
    {
        unsigned a = cvtpk(s[8], s[9]), b = cvtpk(s[12], s[13]);
        plswap(a, b);
        unsigned c = cvtpk(s[10], s[11]), d = cvtpk(s[14], s[15]);
        plswap(c, d);
        u1[0] = a; u1[1] = c; u1[2] = b; u1[3] = d;
    }
    f0 = __builtin_bit_cast(short8, u0);
    f1 = __builtin_bit_cast(short8, u1);
}

// ---------------- fused cast fp32 -> bf16 for x | w_qkv (q-rows scaled) | w_out ----------
__global__ __launch_bounds__(256) void cast3(const float* __restrict__ x,
                                             const float* __restrict__ wqkv,
                                             const float* __restrict__ wout,
                                             u16* __restrict__ dst) {
    const int blk = blockIdx.x;
    const float* src;
    int idx;
    float sc = 1.0f;
    u16* out;
    if (blk < 8192) {
        src = x; out = dst; idx = (blk * 256 + threadIdx.x) * 4;
    } else if (blk < 11264) {
        src = wqkv; out = dst + (size_t)8192 * 1024;
        idx = ((blk - 8192) * 256 + threadIdx.x) * 4;
        if (idx < 1024 * 1024) sc = 0.18033688011112042f;  // 0.125 * log2(e) on q-rows
    } else {
        src = wout; out = dst + (size_t)11264 * 1024;
        idx = ((blk - 11264) * 256 + threadIdx.x) * 4;
    }
    float4 v = *(const float4*)(src + idx);
    u16x4 r;
    r[0] = f2bf(v.x * sc); r[1] = f2bf(v.y * sc);
    r[2] = f2bf(v.z * sc); r[3] = f2bf(v.w * sc);
    *(u16x4*)(out + idx) = r;
}

// ---------------- GEMM1a: Q|K projection, 256x256 tile, BK=64, 8 waves -------------------
// XCD-stripe affinity: xcd = bid&7 owns A-stripes tm in [xcd*4, xcd*4+4) (2 MB, L2-fits).
__global__ __launch_bounds__(512, 2) void gemm256(const u16* __restrict__ A,
                                                  const u16* __restrict__ B,
                                                  u16* __restrict__ qk) {
    __shared__ u16 lds[2][2][16384];   // [dbuf][A=0/B=1][256 rows x 64 cols]
    const int tid = threadIdx.x;
    const int l = tid & 63;
    const int w = tid >> 6;
    const int g = l >> 4, lo = l & 15;
    const int wrow = w >> 2, wcol = w & 3;            // 2 x 4 wave grid
    const int xcd = blockIdx.x & 7, j = blockIdx.x >> 3;   // 256 blocks = 8 XCD x 32
    const int tm = xcd * 4 + (j & 3), tn = j >> 2;         // 4 stripes per XCD, tn 0..7
    const int rowBase = tm << 8, colBase = tn << 8;

    const int srow = tid >> 3;                                        // 0..63
    const int scol = (((tid * 16) ^ (((tid >> 3) & 7) << 4)) & 127) >> 1;  // pre-swizzled col
    const u16* pa = A + (size_t)(rowBase + srow) * 1024 + scol;
    const u16* pb = B + (size_t)(colBase + srow) * 1024 + scol;
    const int ldsOff = tid * 16;

    int abase[2], bbase[2];
#pragma unroll
    for (int k = 0; k < 2; ++k) {
        abase[k] = (((wrow * 128 + lo) * 128 + k * 64 + g * 16) ^ ((lo & 7) << 4));
        bbase[k] = (((wcol * 64 + lo) * 128 + k * 64 + g * 16) ^ ((lo & 7) << 4));
    }

    f32x4 acc[8][4] = {};

#define STAGE256(buf, kt)                                                                   \
    {                                                                                       \
        const u16* sa = pa + (kt) * 64;                                                     \
        const u16* sb = pb + (kt) * 64;                                                     \
        _Pragma("unroll")                                                                   \
        for (int i = 0; i < 4; ++i) {                                                       \
            async16((char*)lds[buf][0] + ldsOff + i * 8192, sa + (size_t)i * 64 * 1024);    \
            async16((char*)lds[buf][1] + ldsOff + i * 8192, sb + (size_t)i * 64 * 1024);    \
        }                                                                                   \
    }

    STAGE256(0, 0);
    __syncthreads();

    for (int kt = 0; kt < 16; ++kt) {
        const int cur = kt & 1;
        if (kt < 15) STAGE256(cur ^ 1, kt + 1);        // issue BEFORE compute (T14/T3)
        const char* la = (const char*)lds[cur][0];
        const char* lb = (const char*)lds[cur][1];

        short8 bf[4][2], af[4][2];
#pragma unroll
        for (int n = 0; n < 4; ++n)
#pragma unroll
            for (int k = 0; k < 2; ++k)
                bf[n][k] = *(const short8*)(lb + bbase[k] + n * 2048);
#pragma unroll
        for (int m = 0; m < 4; ++m)
#pragma unroll
            for (int k = 0; k < 2; ++k)
                af[m][k] = *(const short8*)(la + abase[k] + m * 2048);
        __builtin_amdgcn_s_setprio(1);
#pragma unroll
        for (int m = 0; m < 4; ++m)
#pragma unroll
            for (int n = 0; n < 4; ++n) {
                acc[m][n] = MFMA16(af[m][0], bf[n][0], acc[m][n]);
                acc[m][n] = MFMA16(af[m][1], bf[n][1], acc[m][n]);
            }
        __builtin_amdgcn_s_setprio(0);
#pragma unroll
        for (int m = 0; m < 4; ++m)
#pragma unroll
            for (int k = 0; k < 2; ++k)
                af[m][k] = *(const short8*)(la + abase[k] + (m + 4) * 2048);
        __builtin_amdgcn_s_setprio(1);
#pragma unroll
        for (int m = 0; m < 4; ++m)
#pragma unroll
            for (int n = 0; n < 4; ++n) {
                acc[m + 4][n] = MFMA16(af[m][0], bf[n][0], acc[m + 4][n]);
                acc[m + 4][n] = MFMA16(af[m][1], bf[n][1], acc[m + 4][n]);
            }
        __builtin_amdgcn_s_setprio(0);
        __syncthreads();   // drains this iter's stage (issued one full compute ago)
    }
#undef STAGE256

    // ---- epilogue: Q|K -> qkb (ld 2048) ----
#pragma unroll
    for (int n = 0; n < 4; ++n) {
        const int c = colBase + wcol * 64 + n * 16 + lo;
#pragma unroll
        for (int m = 0; m < 8; ++m) {
            const int r0 = rowBase + wrow * 128 + m * 16 + g * 4;
#pragma unroll
            for (int i = 0; i < 4; ++i)
                qk[(size_t)(r0 + i) * 2048 + c] = f2bf(acc[m][n][i]);
        }
    }
}

// ---------------- GEMM1b: V projection, 128x128 tile, BK=64 (gemm256 swizzle pattern) ----
// LDS [128][64] with T2 XOR swizzle; staged via pre-swizzled source; 16 K-tiles.
__global__ __launch_bounds__(256, 2) void gemmV(const u16* __restrict__ A,
                                                const u16* __restrict__ Bv,
                                                u16* __restrict__ vt) {
    __shared__ u16 As[128 * 64];
    __shared__ u16 Bs[128 * 64];
    const int tid = threadIdx.x;
    const int w = tid >> 6, l = tid & 63;
    const int g = l >> 4, lo = l & 15;
    const int xcd = blockIdx.x & 7, j = blockIdx.x >> 3;   // 8 XCD x 64
    const int tm = xcd * 8 + (j & 7), tn = j >> 3;         // 8 stripes per XCD, tn 0..7
    const int rowBase = tm << 7, colBase = tn << 7;
    const int wrow = w >> 1, wcol = w & 1;

    // staging: 4 instr per matrix; instr i covers rows [i*32, i*32+31]; pre-swizzled col
    const int srow = tid >> 3;                                             // 0..31
    const int scol = (((tid * 16) ^ (((tid >> 3) & 7) << 4)) & 127) >> 1;  // elem col
    const u16* pa = A + (size_t)(rowBase + srow) * 1024 + scol;
    const u16* pb = Bv + (size_t)(colBase + srow) * 1024 + scol;
    const int ldsOff = tid * 16;

    // ds_read byte offsets: frag (row16,k) = base[k] + mi*2048; swizzle ^((lo&7)<<4)
    int abase[2], bbase[2];
#pragma unroll
    for (int k = 0; k < 2; ++k) {
        abase[k] = (((wrow * 64 + lo) * 128 + k * 64 + g * 16) ^ ((lo & 7) << 4));
        bbase[k] = (((wcol * 64 + lo) * 128 + k * 64 + g * 16) ^ ((lo & 7) << 4));
    }

    f32x4 acc[4][4] = {};

    for (int kt = 0; kt < 16; ++kt) {
        const int kbase = kt * 64;
#pragma unroll
        for (int i = 0; i < 4; ++i) {
            async16((char*)As + ldsOff + i * 4096, pa + kbase + (size_t)i * 32 * 1024);
            async16((char*)Bs + ldsOff + i * 4096, pb + kbase + (size_t)i * 32 * 1024);
        }
        __syncthreads();
        short8 af[4][2], bf[4][2];
#pragma unroll
        for (int mi = 0; mi < 4; ++mi)
#pragma unroll
            for (int k = 0; k < 2; ++k)
                af[mi][k] = *(const short8*)((const char*)As + abase[k] + mi * 2048);
#pragma unroll
        for (int ni = 0; ni < 4; ++ni)
#pragma unroll
            for (int k = 0; k < 2; ++k)
                bf[ni][k] = *(const short8*)((const char*)Bs + bbase[k] + ni * 2048);
        __builtin_amdgcn_s_setprio(1);
#pragma unroll
        for (int mi = 0; mi < 4; ++mi)
#pragma unroll
            for (int ni = 0; ni < 4; ++ni) {
                acc[mi][ni] = MFMA16(af[mi][0], bf[ni][0], acc[mi][ni]);
                acc[mi][ni] = MFMA16(af[mi][1], bf[ni][1], acc[mi][ni]);
            }
        __builtin_amdgcn_s_setprio(0);
        __syncthreads();
    }

    // transposed epilogue -> vtg [(b*16+h)*64+d][2048]
    const int b = rowBase >> 11;
#pragma unroll
    for (int ni = 0; ni < 4; ++ni) {
        const int c = colBase + wcol * 64 + ni * 16 + lo;   // 0..1023
        const int hh = c >> 6, d = c & 63;
        u16* vrow = vt + ((size_t)((b * 16 + hh) * 64 + d)) * 2048;
#pragma unroll
        for (int mi = 0; mi < 4; ++mi) {
            const int r0 = rowBase + wrow * 64 + mi * 16 + g * 4;
            u16x4 pk;
#pragma unroll
            for (int i = 0; i < 4; ++i) pk[i] = f2bf(acc[mi][ni][i]);
            *(u16x4*)(vrow + (r0 & 2047)) = pk;
        }
    }
}

// ---------------- GEMM2: 128x128 tile, BK=64 (same pattern), fp32+bias epilogue ----------
__global__ __launch_bounds__(256, 2) void gemm_bt(const u16* __restrict__ A,
                                                  const u16* __restrict__ B,
                                                  float* __restrict__ Cf,
                                                  const float* __restrict__ bias,
                                                  int M, int N, int K) {
    __shared__ u16 As[128 * 64];
    __shared__ u16 Bs[128 * 64];
    const int tid = threadIdx.x;
    const int w = tid >> 6, l = tid & 63;
    const int g = l >> 4, lo = l & 15;
    const int mtiles = M >> 7;
    const int S = mtiles >> 3;
    const int xcd = blockIdx.x & 7, j = blockIdx.x >> 3;
    const int tm = xcd * S + (j % S), tn = j / S;
    const int rowBase = tm << 7, colBase = tn << 7;
    const int wrow = w >> 1, wcol = w & 1;

    const int srow = tid >> 3;
    const int scol = (((tid * 16) ^ (((tid >> 3) & 7) << 4)) & 127) >> 1;
    const u16* pa = A + (size_t)(rowBase + srow) * K + scol;
    const u16* pb = B + (size_t)(colBase + srow) * K + scol;
    const int ldsOff = tid * 16;

    int abase[2], bbase[2];
#pragma unroll
    for (int k = 0; k < 2; ++k) {
        abase[k] = (((wrow * 64 + lo) * 128 + k * 64 + g * 16) ^ ((lo & 7) << 4));
        bbase[k] = (((wcol * 64 + lo) * 128 + k * 64 + g * 16) ^ ((lo & 7) << 4));
    }

    f32x4 acc[4][4] = {};

    const int nk = K >> 6;
    for (int kt = 0; kt < nk; ++kt) {
        const int kbase = kt * 64;
#pragma unroll
        for (int i = 0; i < 4; ++i) {
            async16((char*)As + ldsOff + i * 4096, pa + kbase + (size_t)i * 32 * K);
            async16((char*)Bs + ldsOff + i * 4096, pb + kbase + (size_t)i * 32 * K);
        }
        __syncthreads();
        short8 af[4][2], bf[4][2];
#pragma unroll
        for (int mi = 0; mi < 4; ++mi)
#pragma unroll
            for (int k = 0; k < 2; ++k)
                af[mi][k] = *(const short8*)((const char*)As + abase[k] + mi * 2048);
#pragma unroll
        for (int ni = 0; ni < 4; ++ni)
#pragma unroll
            for (int k = 0; k < 2; ++k)
                bf[ni][k] = *(const short8*)((const char*)Bs + bbase[k] + ni * 2048);
        __builtin_amdgcn_s_setprio(1);
#pragma unroll
        for (int mi = 0; mi < 4; ++mi)
#pragma unroll
            for (int ni = 0; ni < 4; ++ni) {
                acc[mi][ni] = MFMA16(af[mi][0], bf[ni][0], acc[mi][ni]);
                acc[mi][ni] = MFMA16(af[mi][1], bf[ni][1], acc[mi][ni]);
            }
        __builtin_amdgcn_s_setprio(0);
        __syncthreads();
    }

#pragma unroll
    for (int ni = 0; ni < 4; ++ni) {
        const int c = colBase + wcol * 64 + ni * 16 + lo;
        const float bv = bias[c];
#pragma unroll
        for (int mi = 0; mi < 4; ++mi) {
            const int r0 = rowBase + wrow * 64 + mi * 16 + g * 4;
#pragma unroll
            for (int i = 0; i < 4; ++i)
                Cf[(size_t)(r0 + i) * N + c] = acc[mi][ni][i] + bv;
        }
    }
}

// ---------------- flash attention (round-12 verified, verbatim) --------------------------
// 256 q-rows/block, KVBLK=128 as 2x64 chunks, 2 subtiles sharing K/V register fragments.
__global__ __launch_bounds__(256, 2) void attn_fwd(const u16* __restrict__ qkb,
                                                   const u16* __restrict__ vtg,
                                                   u16* __restrict__ outb) {
    __shared__ u16 Ks[2][2][4096];   // [dbuf][chunk][64 keys x 64 d]
    __shared__ u16 Vs[2][2][4096];   // [dbuf][chunk][64 d x 64 keys]
    const int tid = threadIdx.x;
    const int w = tid >> 6, l = tid & 63;
    const int hi = l >> 5, lq = l & 31;

    const int lin = (blockIdx.x & 7) * 64 + (blockIdx.x >> 3);  // bijective XCD chunking
    const int bh = lin >> 3, qt = lin & 7;
    const int b = bh >> 4, h = bh & 15;
    const size_t rowQ0 = (size_t)b * 2048 + qt * 256 + w * 32;  // subtile 0 rows
    const size_t rowQ1 = rowQ0 + 128;                           // subtile 1 rows

    short8 qf0[4], qf1[4];
#pragma unroll
    for (int ks = 0; ks < 4; ++ks) {
        qf0[ks] = *(const short8*)(qkb + (rowQ0 + lq) * 2048 + h * 64 + ks * 16 + hi * 8);
        qf1[ks] = *(const short8*)(qkb + (rowQ1 + lq) * 2048 + h * 64 + ks * 16 + hi * 8);
    }

    int koff[4];
#pragma unroll
    for (int ks = 0; ks < 4; ++ks)
        koff[ks] = (lq * 128 + ks * 32 + hi * 16) ^ ((lq & 7) << 4);

    const int L0 = tid * 16, L1 = tid * 16 + 4096;
    const int kr0 = L0 >> 7, kc0 = ((L0 ^ ((kr0 & 7) << 4)) & 127) >> 1;
    const int kr1 = L1 >> 7, kc1 = ((L1 ^ ((kr1 & 7) << 4)) & 127) >> 1;
    const u16* ks0 = qkb + (size_t)(b * 2048 + kr0) * 2048 + 1024 + h * 64 + kc0;
    const u16* ks1 = qkb + (size_t)(b * 2048 + kr1) * 2048 + 1024 + h * 64 + kc1;
    const u16* vs0 = vtg + ((size_t)bh * 64 + kr0) * 2048 + kc0;
    const u16* vs1 = vtg + ((size_t)bh * 64 + kr1) * 2048 + kc1;
    const size_t KADV = (size_t)128 * 2048;   // 128 key-rows per tile
    const size_t CADV = (size_t)64 * 2048;    // chunk-1 key-row offset

    f32x16 O00, O01, Ol0, O10, O11, Ol1;
#pragma unroll
    for (int i = 0; i < 16; ++i) {
        O00[i] = 0.f; O01[i] = 0.f; Ol0[i] = 0.f;
        O10[i] = 0.f; O11[i] = 0.f; Ol1[i] = 0.f;
    }
    const f32x16 Z = {};
    const short8 onesv = {16256, 16256, 16256, 16256, 16256, 16256, 16256, 16256}; // bf16 1.0

#define STAGEKV(buf)                                                        \
    {                                                                       \
        async16((char*)Ks[buf][0] + L0, ks0);                               \
        async16((char*)Ks[buf][0] + L1, ks1);                               \
        async16((char*)Ks[buf][1] + L0, ks0 + CADV);                        \
        async16((char*)Ks[buf][1] + L1, ks1 + CADV);                        \
        async16((char*)Vs[buf][0] + L0, vs0);                               \
        async16((char*)Vs[buf][0] + L1, vs1);                               \
        async16((char*)Vs[buf][1] + L0, vs0 + 64);                          \
        async16((char*)Vs[buf][1] + L1, vs1 + 64);                          \
        ks0 += KADV; ks1 += KADV; vs0 += 128; vs1 += 128;                   \
    }

    STAGEKV(0);

    int cur = 0;
    for (int kt = 0; kt < 16; ++kt) {      // 16 tiles x 128 keys
        __syncthreads();
        if (kt < 15) STAGEKV(cur ^ 1);

#pragma unroll
        for (int c = 0; c < 2; ++c) {                 // 64-key chunks
            const char* kb = (const char*)Ks[cur][c];
            const char* vb = (const char*)Vs[cur][c];

#pragma unroll
            for (int t = 0; t < 2; ++t) {             // key-halves (32 keys each)
                const int tb = t * 4096;
                short8 kf0 = *(const short8*)(kb + koff[0] + tb);
                short8 kf1 = *(const short8*)(kb + koff[1] + tb);
                short8 kf2 = *(const short8*)(kb + koff[2] + tb);
                short8 kf3 = *(const short8*)(kb + koff[3] + tb);
                short8 vfa = *(const short8*)(vb + koff[t * 2]);
                short8 vfb = *(const short8*)(vb + koff[t * 2] + 4096);
                short8 vfc = *(const short8*)(vb + koff[t * 2 + 1]);
                short8 vfd = *(const short8*)(vb + koff[t * 2 + 1] + 4096);

                // ======== subtile 0: verified chain (single S live) ========
                {
                    __builtin_amdgcn_s_setprio(1);
                    f32x16 s = MFMA32(kf0, qf0[0], Z);
                    s = MFMA32(kf1, qf0[1], s);
                    s = MFMA32(kf2, qf0[2], s);
                    s = MFMA32(kf3, qf0[3], s);
                    __builtin_amdgcn_s_setprio(0);
#pragma unroll
                    for (int i = 0; i < 16; ++i) s[i] = EXP2F(s[i]);
                    short8 p0, p1;
                    packP(s, p0, p1);
                    __builtin_amdgcn_s_setprio(1);
                    Ol0 = MFMA32(p0, onesv, Ol0);
                    Ol0 = MFMA32(p1, onesv, Ol0);
                    O00 = MFMA32(p0, vfa, O00);
                    O01 = MFMA32(p0, vfb, O01);
                    O00 = MFMA32(p1, vfc, O00);
                    O01 = MFMA32(p1, vfd, O01);
                    __builtin_amdgcn_s_setprio(0);
                }
                // ======== subtile 1: same chain, same kf/vf regs ========
                {
                    __builtin_amdgcn_s_setprio(1);
                    f32x16 s = MFMA32(kf0, qf1[0], Z);
                    s = MFMA32(kf1, qf1[1], s);
                    s = MFMA32(kf2, qf1[2], s);
                    s = MFMA32(kf3, qf1[3], s);
                    __builtin_amdgcn_s_setprio(0);
#pragma unroll
                    for (int i = 0; i < 16; ++i) s[i] = EXP2F(s[i]);
                    short8 p0, p1;
                    packP(s, p0, p1);
                    __builtin_amdgcn_s_setprio(1);
                    Ol1 = MFMA32(p0, onesv, Ol1);
                    Ol1 = MFMA32(p1, onesv, Ol1);
                    O10 = MFMA32(p0, vfa, O10);
                    O11 = MFMA32(p0, vfb, O11);
                    O10 = MFMA32(p1, vfc, O10);
                    O11 = MFMA32(p1, vfd, O11);
                    __builtin_amdgcn_s_setprio(0);
                }
            }
        }
        cur ^= 1;
    }
#undef STAGEKV

    // ---- epilogue: normalize by Ol, store bf16 (both subtiles) ----
#pragma unroll
    for (int r = 0; r < 16; ++r) {
        const int qrow = (r & 3) + 8 * (r >> 2) + 4 * hi;
        {
            const float linv = 1.0f / Ol0[r];
            u16* op = outb + (rowQ0 + qrow) * 1024 + h * 64 + lq;
            op[0] = f2bf(O00[r] * linv);
            op[32] = f2bf(O01[r] * linv);
        }
        {
            const float linv = 1.0f / Ol1[r];
            u16* op = outb + (rowQ1 + qrow) * 1024 + h * 64 + lq;
            op[0] = f2bf(O10[r] * linv);
            op[32] = f2bf(O11[r] * linv);
        }
    }
}

// ---------------- launch ----------------------------------------------------------------
extern "C" void kernel_launch(void* const* d_in, const int* in_sizes, int n_in,
                              void* d_out, int out_size, void* d_ws, size_t ws_size,
                              hipStream_t stream) {
    const float* x     = (const float*)d_in[0];   // [4,2048,1024]
    const float* w_qkv = (const float*)d_in[1];   // [3072,1024]
    const float* w_out = (const float*)d_in[2];   // [1024,1024]
    const float* b_out = (const float*)d_in[3];   // [1024]
    float* out = (float*)d_out;                   // [4,2048,1024] fp32

    u16* xb    = (u16*)d_ws;                              // 8192*1024
    u16* wqkvb = xb    + (size_t)8192 * 1024;             // 3072*1024
    u16* woutb = wqkvb + (size_t)3072 * 1024;             // 1024*1024
    u16* qkb   = woutb + (size_t)1024 * 1024;             // 8192*2048 (Q|K)
    u16* vtg   = qkb   + (size_t)8192 * 2048;             // 64*64*2048 (V^T per bh)
    u16* attb  = vtg   + (size_t)64 * 64 * 2048;          // 8192*1024
    // total ws use: 92,274,688 bytes

    cast3<<<12288, 256, 0, stream>>>(x, w_qkv, w_out, xb);

    gemm256<<<256, 512, 0, stream>>>(xb, wqkvb, qkb);                 // Q|K projection
    gemmV<<<512, 256, 0, stream>>>(xb, wqkvb + (size_t)2048 * 1024, vtg);  // V projection

    attn_fwd<<<512, 256, 0, stream>>>(qkb, vtg, attb);

    gemm_bt<<<dim3((8192 / 128) * (1024 / 128)), 256, 0, stream>>>(
        attb, woutb, out, b_out, 8192, 1024, 1024);
}